// Round 1
// baseline (694.049 us; speedup 1.0000x reference)
//
#include <hip/hip_runtime.h>
#include <hip/hip_bf16.h>
#include <math.h>

#define B_ 8
#define N_ 512
#define K_ 16
#define D_ 256
#define F_ 1024
#define H_ 8
#define HD_ 32
#define M_ (B_*N_)      // 4096 rows (b,n)
#define R_ (B_*N_*K_)   // 65536 edge rows
#define RC_ 8192        // edge MLP chunk rows
#define NCH_ (R_/RC_)   // 8 chunks

typedef __bf16 bf16x8 __attribute__((ext_vector_type(8)));
typedef float  f32x4  __attribute__((ext_vector_type(4)));

__device__ inline short bf16s(float f) {
    __hip_bfloat16 h = __float2bfloat16(f);
    return *reinterpret_cast<short*>(&h);
}

// ---------------- weight transpose+convert: W[K][N] f32 -> WT[N][K] bf16 ----
__global__ __launch_bounds__(256) void transposeW(const float* __restrict__ W,
        short* __restrict__ WT, int Kk, int Nn)
{
    __shared__ float tile[32][33];
    int bx = blockIdx.x;          // along N
    int by = blockIdx.y;          // along K
    int tx = threadIdx.x & 31, ty = threadIdx.x >> 5;   // 32x8
    #pragma unroll
    for (int j = 0; j < 4; ++j) {
        int k = by*32 + ty + j*8;
        tile[ty + j*8][tx] = W[(size_t)k*Nn + bx*32 + tx];
    }
    __syncthreads();
    #pragma unroll
    for (int j = 0; j < 4; ++j) {
        int n = bx*32 + ty + j*8;
        WT[(size_t)n*Kk + by*32 + tx] = bf16s(tile[tx][ty + j*8]);
    }
}

// ---------------- x (N,B,D) f32 -> xtb (B*N, D) bf16 ------------------------
__global__ __launch_bounds__(256) void conv_x(const float* __restrict__ x,
        short* __restrict__ xtb)
{
    int row = blockIdx.x;         // b*N+n
    int d = threadIdx.x;
    int b = row / N_, n = row % N_;
    xtb[(size_t)row*D_ + d] = bf16s(x[((size_t)n*B_ + b)*D_ + d]);
}

// ---------------- means[b,i,k] = mean_d e ----------------------------------
__global__ __launch_bounds__(256) void edge_means(const float* __restrict__ e,
        float* __restrict__ means)
{
    long row = (long)blockIdx.x*4 + (threadIdx.x >> 6);
    int lane = threadIdx.x & 63;
    const float* p = e + row*D_;
    float s = 0.f;
    #pragma unroll
    for (int j = 0; j < 4; ++j) s += p[lane + j*64];
    for (int o = 1; o < 64; o <<= 1) s += __shfl_xor(s, o);
    if (lane == 0) means[row] = s * (1.f/D_);
}

__global__ __launch_bounds__(256) void zero4(float4* __restrict__ p, long n4)
{
    long i = (long)blockIdx.x*256 + threadIdx.x;
    if (i < n4) p[i] = make_float4(0.f, 0.f, 0.f, 0.f);
}

// serial per (b,i): numpy last-wins duplicate semantics
__global__ __launch_bounds__(256) void scatter_bias(const int* __restrict__ ei,
        const float* __restrict__ means, float* __restrict__ biasb)
{
    int idx = blockIdx.x*256 + threadIdx.x;   // b*N+i
    if (idx >= B_*N_) return;
    const int* ep = ei + (size_t)idx*K_;
    const float* mp = means + (size_t)idx*K_;
    float* bp = biasb + (size_t)idx*N_;
    for (int k = 0; k < K_; ++k) bp[ep[k]] = mp[k];
}

// ---------------- generic bf16 MFMA GEMM: C = A[M,K] @ WT[N,K]^T + bias -----
template<bool GELU, bool SCALE, bool OUTF, bool OUTB>
__global__ __launch_bounds__(256) void gemm_bf16(
        const short* __restrict__ A, const short* __restrict__ WT,
        const float* __restrict__ bias, float* __restrict__ Cf,
        short* __restrict__ Cb, int M, int Nn, int Kk, float scale)
{
    (void)M;
    __shared__ __align__(16) short As[128*32];
    __shared__ __align__(16) short Bs[128*32];
    const int t = threadIdx.x;
    const int lane = t & 63;
    const int wave = t >> 6;
    const int wr = (wave >> 1) * 64;
    const int wc = (wave & 1) * 64;
    const int bm = blockIdx.x, bn = blockIdx.y;
    f32x4 acc[4][4] = {};
    const int ar = t >> 2;           // staging row 0..63
    const int ak = (t & 3) * 8;      // staging k offset
    const size_t Abase = (size_t)bm*128*Kk + (size_t)ar*Kk + ak;
    const size_t Bbase = (size_t)bn*128*Kk + (size_t)ar*Kk + ak;
    const int fr = lane & 15;
    const int fk = (lane >> 4) * 8;
    for (int k0 = 0; k0 < Kk; k0 += 32) {
        __syncthreads();
        *(bf16x8*)&As[ar*32 + ak]        = *(const bf16x8*)(A  + Abase + k0);
        *(bf16x8*)&As[(ar+64)*32 + ak]   = *(const bf16x8*)(A  + Abase + (size_t)64*Kk + k0);
        *(bf16x8*)&Bs[ar*32 + ak]        = *(const bf16x8*)(WT + Bbase + k0);
        *(bf16x8*)&Bs[(ar+64)*32 + ak]   = *(const bf16x8*)(WT + Bbase + (size_t)64*Kk + k0);
        __syncthreads();
        bf16x8 af[4], bfr[4];
        #pragma unroll
        for (int i2 = 0; i2 < 4; ++i2)
            af[i2] = *(const bf16x8*)&As[(wr + i2*16 + fr)*32 + fk];
        #pragma unroll
        for (int n2 = 0; n2 < 4; ++n2)
            bfr[n2] = *(const bf16x8*)&Bs[(wc + n2*16 + fr)*32 + fk];
        #pragma unroll
        for (int i2 = 0; i2 < 4; ++i2)
            #pragma unroll
            for (int n2 = 0; n2 < 4; ++n2)
                acc[i2][n2] = __builtin_amdgcn_mfma_f32_16x16x32_bf16(
                        af[i2], bfr[n2], acc[i2][n2], 0, 0, 0);
    }
    const int fq4 = (lane >> 4) * 4;
    #pragma unroll
    for (int i2 = 0; i2 < 4; ++i2) {
        #pragma unroll
        for (int n2 = 0; n2 < 4; ++n2) {
            const int col = bn*128 + wc + n2*16 + fr;
            const float bv = bias[col];
            #pragma unroll
            for (int r2 = 0; r2 < 4; ++r2) {
                const int row = bm*128 + wr + i2*16 + fq4 + r2;
                float v = acc[i2][n2][r2] + bv;
                if constexpr (SCALE) v *= scale;
                if constexpr (GELU)  v = 0.5f*v*(1.f + erff(v*0.70710678118654752f));
                if constexpr (OUTF)  Cf[(size_t)row*Nn + col] = v;
                if constexpr (OUTB)  Cb[(size_t)row*Nn + col] = bf16s(v);
            }
        }
    }
}

// ---------------- attention logits: probs[b,h,i,j] = q.k + bias[b,i,j] ------
__global__ __launch_bounds__(256) void attn_logits(const float* __restrict__ q,
        const float* __restrict__ kk, const float* __restrict__ biasb,
        float* __restrict__ probs)
{
    int bh = blockIdx.x; int b = bh / H_, h = bh % H_;
    int it = blockIdx.y;
    __shared__ float qs[64][33];
    __shared__ float ks[64][33];
    int t = threadIdx.x;
    int r = t >> 2, dd = (t & 3) * 8;
    const size_t qbase = ((size_t)b*N_ + it*64 + r)*D_ + h*HD_ + dd;
    #pragma unroll
    for (int j = 0; j < 8; ++j) qs[r][dd + j] = q[qbase + j];
    int i = t >> 2;
    int j0 = (t & 3) * 16;
    size_t orow = ((size_t)bh*N_ + it*64 + i)*N_;
    size_t brow = ((size_t)b*N_ + it*64 + i)*N_;
    for (int jt = 0; jt < N_/64; ++jt) {
        __syncthreads();
        const size_t kbase = ((size_t)b*N_ + jt*64 + r)*D_ + h*HD_ + dd;
        #pragma unroll
        for (int j = 0; j < 8; ++j) ks[r][dd + j] = kk[kbase + j];
        __syncthreads();
        for (int jj = j0; jj < j0 + 16; ++jj) {
            float s = 0.f;
            #pragma unroll
            for (int d2 = 0; d2 < HD_; ++d2) s += qs[i][d2] * ks[jj][d2];
            probs[orow + jt*64 + jj] = s + biasb[brow + jt*64 + jj];
        }
    }
}

// ---------------- row softmax over 512 --------------------------------------
__global__ __launch_bounds__(256) void softmax_rows(float* __restrict__ p)
{
    size_t row = blockIdx.x;
    float* rp = p + row*N_;
    int t = threadIdx.x;
    float v0 = rp[t], v1 = rp[t + 256];
    float m = fmaxf(v0, v1);
    for (int o = 1; o < 64; o <<= 1) m = fmaxf(m, __shfl_xor(m, o));
    __shared__ float rmax[4], rsum[4];
    if ((t & 63) == 0) rmax[t >> 6] = m;
    __syncthreads();
    m = fmaxf(fmaxf(rmax[0], rmax[1]), fmaxf(rmax[2], rmax[3]));
    float e0 = expf(v0 - m), e1 = expf(v1 - m);
    float s = e0 + e1;
    for (int o = 1; o < 64; o <<= 1) s += __shfl_xor(s, o);
    if ((t & 63) == 0) rsum[t >> 6] = s;
    __syncthreads();
    s = rsum[0] + rsum[1] + rsum[2] + rsum[3];
    float inv = 1.f / s;
    rp[t] = e0 * inv; rp[t + 256] = e1 * inv;
}

// ---------------- head mean: wmean[b,i,j] = mean_h probs ---------------------
__global__ __launch_bounds__(256) void head_mean(const float* __restrict__ probs,
        float* __restrict__ wmean)
{
    long idx = (long)blockIdx.x*256 + threadIdx.x;   // b*N*N + i*N + j
    if (idx >= (long)B_*N_*N_) return;
    long b = idx / ((long)N_*N_);
    long rem = idx - b*(long)N_*N_;
    const float* pp = probs + (size_t)b*H_*N_*N_ + rem;
    float s = 0.f;
    #pragma unroll
    for (int h = 0; h < H_; ++h) s += pp[(size_t)h*N_*N_];
    wmean[idx] = s * (1.f/H_);
}

// ---------------- PV: actx[b,n,h*32+dh] = sum_m probs * v (bf16 out) --------
__global__ __launch_bounds__(256) void attn_pv(const float* __restrict__ probs,
        const float* __restrict__ vf, short* __restrict__ actx)
{
    int bh = blockIdx.x; int b = bh / H_, h = bh % H_;
    int it = blockIdx.y;
    __shared__ float aS[64][65];
    __shared__ float vS[64][33];
    int t = threadIdx.x;
    int r = t >> 2;
    int dd8 = (t & 3) * 8;
    int mm0 = (t & 3) * 16;
    int nl = t >> 2;
    float acc[8] = {};
    for (int mt = 0; mt < N_/64; ++mt) {
        __syncthreads();
        const size_t prow = ((size_t)bh*N_ + it*64 + r)*N_ + mt*64 + mm0;
        #pragma unroll
        for (int j = 0; j < 16; ++j) aS[r][mm0 + j] = probs[prow + j];
        const size_t vrow = ((size_t)b*N_ + mt*64 + r)*D_ + h*HD_ + dd8;
        #pragma unroll
        for (int j = 0; j < 8; ++j) vS[r][dd8 + j] = vf[vrow + j];
        __syncthreads();
        for (int m2 = 0; m2 < 64; ++m2) {
            float a = aS[nl][m2];
            #pragma unroll
            for (int j = 0; j < 8; ++j) acc[j] += a * vS[m2][dd8 + j];
        }
    }
    const size_t obase = ((size_t)b*N_ + it*64 + nl)*D_ + h*HD_ + dd8;
    #pragma unroll
    for (int j = 0; j < 8; ++j) actx[obase + j] = bf16s(acc[j]);
}

// ---------------- LN helpers (wave per row of 256) ---------------------------
__device__ inline void ln_core(float v[4], int lane, const float* __restrict__ g,
        const float* __restrict__ bt, float out[4])
{
    float s  = v[0] + v[1] + v[2] + v[3];
    float sq = v[0]*v[0] + v[1]*v[1] + v[2]*v[2] + v[3]*v[3];
    for (int o = 1; o < 64; o <<= 1) { s += __shfl_xor(s, o); sq += __shfl_xor(sq, o); }
    float mean = s * (1.f/D_);
    float rstd = rsqrtf(sq * (1.f/D_) - mean*mean + 1e-5f);
    const float4 gv = *(const float4*)(g  + lane*4);
    const float4 bv = *(const float4*)(bt + lane*4);
    out[0] = (v[0]-mean)*rstd*gv.x + bv.x;
    out[1] = (v[1]-mean)*rstd*gv.y + bv.y;
    out[2] = (v[2]-mean)*rstd*gv.z + bv.z;
    out[3] = (v[3]-mean)*rstd*gv.w + bv.w;
}

// xn = LN(x^T + aout); writes f32 + bf16
__global__ __launch_bounds__(256) void ln_xn(const float* __restrict__ x,
        const float* __restrict__ aout, const float* __restrict__ g,
        const float* __restrict__ bt, float* __restrict__ xn, short* __restrict__ xnb)
{
    int row = blockIdx.x*4 + (threadIdx.x >> 6);
    int lane = threadIdx.x & 63;
    int b = row / N_, n = row % N_;
    const float4 xv = *(const float4*)(x + ((size_t)n*B_ + b)*D_ + lane*4);
    const float4 av = *(const float4*)(aout + (size_t)row*D_ + lane*4);
    float v[4] = {xv.x+av.x, xv.y+av.y, xv.z+av.z, xv.w+av.w};
    float o[4];
    ln_core(v, lane, g, bt, o);
    *(float4*)(xn + (size_t)row*D_ + lane*4) = make_float4(o[0], o[1], o[2], o[3]);
    short4 s4; s4.x = bf16s(o[0]); s4.y = bf16s(o[1]); s4.z = bf16s(o[2]); s4.w = bf16s(o[3]);
    *(short4*)(xnb + (size_t)row*D_ + lane*4) = s4;
}

// out1 (N,B,D) = LN(xn + nmlp)
__global__ __launch_bounds__(256) void ln_node_final(const float* __restrict__ xn,
        const float* __restrict__ nmlp, const float* __restrict__ g,
        const float* __restrict__ bt, float* __restrict__ out1)
{
    int row = blockIdx.x*4 + (threadIdx.x >> 6);
    int lane = threadIdx.x & 63;
    int b = row / N_, n = row % N_;
    const float4 a = *(const float4*)(xn   + (size_t)row*D_ + lane*4);
    const float4 m = *(const float4*)(nmlp + (size_t)row*D_ + lane*4);
    float v[4] = {a.x+m.x, a.y+m.y, a.z+m.z, a.w+m.w};
    float o[4];
    ln_core(v, lane, g, bt, o);
    *(float4*)(out1 + ((size_t)n*B_ + b)*D_ + lane*4) = make_float4(o[0], o[1], o[2], o[3]);
}

// e2 = LN(e + w*gathered); writes f32 (d_out region) + bf16
__global__ __launch_bounds__(256) void edge_update(const float* __restrict__ e,
        const float* __restrict__ x, const int* __restrict__ ei,
        const float* __restrict__ wmean, const float* __restrict__ g,
        const float* __restrict__ bt, float* __restrict__ e2f, short* __restrict__ e2b)
{
    long row = (long)blockIdx.x*4 + (threadIdx.x >> 6);   // b*N*K + i*K + k
    int lane = threadIdx.x & 63;
    long bi = row >> 4;          // / K_
    long b = bi / N_; int i = (int)(bi % N_);
    int ej = ei[row];
    float w = wmean[((size_t)b*N_ + ej)*N_ + i];
    const float4 ev = *(const float4*)(e + row*D_ + lane*4);
    const float4 xv = *(const float4*)(x + ((size_t)ej*B_ + b)*D_ + lane*4);
    float v[4] = {ev.x + w*xv.x, ev.y + w*xv.y, ev.z + w*xv.z, ev.w + w*xv.w};
    float o[4];
    ln_core(v, lane, g, bt, o);
    *(float4*)(e2f + row*D_ + lane*4) = make_float4(o[0], o[1], o[2], o[3]);
    short4 s4; s4.x = bf16s(o[0]); s4.y = bf16s(o[1]); s4.z = bf16s(o[2]); s4.w = bf16s(o[3]);
    *(short4*)(e2b + row*D_ + lane*4) = s4;
}

// final: e2f = LN(e2f + emlp)   (in-place per row, chunked)
__global__ __launch_bounds__(256) void ln_edge_final(float* __restrict__ e2f,
        const float* __restrict__ emlp, const float* __restrict__ g,
        const float* __restrict__ bt, long R0)
{
    long r = (long)blockIdx.x*4 + (threadIdx.x >> 6);
    long row = R0 + r;
    int lane = threadIdx.x & 63;
    const float4 a = *(const float4*)(e2f  + row*D_ + lane*4);
    const float4 m = *(const float4*)(emlp + r*D_ + lane*4);
    float v[4] = {a.x+m.x, a.y+m.y, a.z+m.z, a.w+m.w};
    float o[4];
    ln_core(v, lane, g, bt, o);
    *(float4*)(e2f + row*D_ + lane*4) = make_float4(o[0], o[1], o[2], o[3]);
}

// ============================================================================
extern "C" void kernel_launch(void* const* d_in, const int* in_sizes, int n_in,
                              void* d_out, int out_size, void* d_ws, size_t ws_size,
                              hipStream_t stream)
{
    (void)in_sizes; (void)n_in; (void)out_size; (void)ws_size;
    const float* x    = (const float*)d_in[0];
    const float* e    = (const float*)d_in[1];
    const int*   ei   = (const int*)d_in[2];
    const float* Wq   = (const float*)d_in[3];
    const float* bq   = (const float*)d_in[4];
    const float* Wk   = (const float*)d_in[5];
    const float* bk   = (const float*)d_in[6];
    const float* Wv   = (const float*)d_in[7];
    const float* bv   = (const float*)d_in[8];
    const float* Wo   = (const float*)d_in[9];
    const float* bo   = (const float*)d_in[10];
    const float* nW1  = (const float*)d_in[11];
    const float* nb1  = (const float*)d_in[12];
    const float* nW2  = (const float*)d_in[13];
    const float* nb2  = (const float*)d_in[14];
    const float* eW1  = (const float*)d_in[15];
    const float* eb1  = (const float*)d_in[16];
    const float* eW2  = (const float*)d_in[17];
    const float* eb2  = (const float*)d_in[18];
    const float* na_g = (const float*)d_in[19];
    const float* na_b = (const float*)d_in[20];
    const float* ea_g = (const float*)d_in[21];
    const float* ea_b = (const float*)d_in[22];
    const float* nf_g = (const float*)d_in[23];
    const float* nf_b = (const float*)d_in[24];
    const float* ef_g = (const float*)d_in[25];
    const float* ef_b = (const float*)d_in[26];

    float* out1 = (float*)d_out;                       // (N,B,D)
    float* e2f  = out1 + (size_t)N_*B_*D_;             // (B,N,K,D) — also e2 intermediate

    char* wp = (char*)d_ws;
    auto alloc = [&](size_t bytes) -> char* {
        char* p = wp; wp += (bytes + 255) & ~(size_t)255; return p;
    };
    short* xtb   = (short*)alloc((size_t)M_*D_*2);
    short* WqT   = (short*)alloc((size_t)D_*D_*2);
    short* WkT   = (short*)alloc((size_t)D_*D_*2);
    short* WvT   = (short*)alloc((size_t)D_*D_*2);
    short* WoT   = (short*)alloc((size_t)D_*D_*2);
    short* nW1T  = (short*)alloc((size_t)D_*F_*2);
    short* nW2T  = (short*)alloc((size_t)D_*F_*2);
    short* eW1T  = (short*)alloc((size_t)D_*F_*2);
    short* eW2T  = (short*)alloc((size_t)D_*F_*2);
    float* means = (float*)alloc((size_t)R_*4);
    float* biasb = (float*)alloc((size_t)B_*N_*N_*4);
    float* qf    = (float*)alloc((size_t)M_*D_*4);
    float* kf    = (float*)alloc((size_t)M_*D_*4);
    float* vf    = (float*)alloc((size_t)M_*D_*4);
    float* probs = (float*)alloc((size_t)B_*H_*N_*N_*4);
    float* wmean = (float*)alloc((size_t)B_*N_*N_*4);
    short* actx  = (short*)alloc((size_t)M_*D_*2);
    float* aout  = (float*)alloc((size_t)M_*D_*4);
    float* xn    = (float*)alloc((size_t)M_*D_*4);
    short* xnb   = (short*)alloc((size_t)M_*D_*2);
    short* nhid  = (short*)alloc((size_t)M_*F_*2);
    float* nmlp  = (float*)alloc((size_t)M_*D_*4);
    short* e2b   = (short*)alloc((size_t)R_*D_*2);
    short* ehid  = (short*)alloc((size_t)RC_*F_*2);
    float* emlp  = (float*)alloc((size_t)RC_*D_*4);

    // ---- weight prep ----
    transposeW<<<dim3(D_/32, D_/32), 256, 0, stream>>>(Wq, WqT, D_, D_);
    transposeW<<<dim3(D_/32, D_/32), 256, 0, stream>>>(Wk, WkT, D_, D_);
    transposeW<<<dim3(D_/32, D_/32), 256, 0, stream>>>(Wv, WvT, D_, D_);
    transposeW<<<dim3(D_/32, D_/32), 256, 0, stream>>>(Wo, WoT, D_, D_);
    transposeW<<<dim3(F_/32, D_/32), 256, 0, stream>>>(nW1, nW1T, D_, F_);
    transposeW<<<dim3(D_/32, F_/32), 256, 0, stream>>>(nW2, nW2T, F_, D_);
    transposeW<<<dim3(F_/32, D_/32), 256, 0, stream>>>(eW1, eW1T, D_, F_);
    transposeW<<<dim3(D_/32, F_/32), 256, 0, stream>>>(eW2, eW2T, F_, D_);
    conv_x<<<M_, 256, 0, stream>>>(x, xtb);

    // ---- attn bias ----
    edge_means<<<R_/4, 256, 0, stream>>>(e, means);
    zero4<<<(int)(((size_t)B_*N_*N_/4 + 255)/256), 256, 0, stream>>>((float4*)biasb, (long)B_*N_*N_/4);
    scatter_bias<<<(M_ + 255)/256, 256, 0, stream>>>(ei, means, biasb);

    // ---- QKV ----
    gemm_bf16<false,true ,true ,false><<<dim3(M_/128, D_/128), 256, 0, stream>>>(
            xtb, WqT, bq, qf, nullptr, M_, D_, D_, 0.17677669529663687f);
    gemm_bf16<false,false,true ,false><<<dim3(M_/128, D_/128), 256, 0, stream>>>(
            xtb, WkT, bk, kf, nullptr, M_, D_, D_, 1.f);
    gemm_bf16<false,false,true ,false><<<dim3(M_/128, D_/128), 256, 0, stream>>>(
            xtb, WvT, bv, vf, nullptr, M_, D_, D_, 1.f);

    // ---- attention ----
    attn_logits<<<dim3(B_*H_, N_/64), 256, 0, stream>>>(qf, kf, biasb, probs);
    softmax_rows<<<B_*H_*N_, 256, 0, stream>>>(probs);
    head_mean<<<(int)(((size_t)B_*N_*N_ + 255)/256), 256, 0, stream>>>(probs, wmean);
    attn_pv<<<dim3(B_*H_, N_/64), 256, 0, stream>>>(probs, vf, actx);
    gemm_bf16<false,false,true ,false><<<dim3(M_/128, D_/128), 256, 0, stream>>>(
            actx, WoT, bo, aout, nullptr, M_, D_, D_, 1.f);

    // ---- node path ----
    ln_xn<<<M_/4, 256, 0, stream>>>(x, aout, na_g, na_b, xn, xnb);
    gemm_bf16<true ,false,false,true ><<<dim3(M_/128, F_/128), 256, 0, stream>>>(
            xnb, nW1T, nb1, nullptr, nhid, M_, F_, D_, 1.f);
    gemm_bf16<false,false,true ,false><<<dim3(M_/128, D_/128), 256, 0, stream>>>(
            nhid, nW2T, nb2, nmlp, nullptr, M_, D_, F_, 1.f);
    ln_node_final<<<M_/4, 256, 0, stream>>>(xn, nmlp, nf_g, nf_b, out1);

    // ---- edge path ----
    edge_update<<<R_/4, 256, 0, stream>>>(e, x, ei, wmean, ea_g, ea_b, e2f, e2b);
    for (int c = 0; c < NCH_; ++c) {
        const short* Ae = e2b + (size_t)c*RC_*D_;
        gemm_bf16<true ,false,false,true ><<<dim3(RC_/128, F_/128), 256, 0, stream>>>(
                Ae, eW1T, eb1, nullptr, ehid, RC_, F_, D_, 1.f);
        gemm_bf16<false,false,true ,false><<<dim3(RC_/128, D_/128), 256, 0, stream>>>(
                ehid, eW2T, eb2, emlp, nullptr, RC_, D_, F_, 1.f);
        ln_edge_final<<<RC_/4, 256, 0, stream>>>(e2f, emlp, ef_g, ef_b, (long)c*RC_);
    }
}

// Round 2
// 481.897 us; speedup vs baseline: 1.4402x; 1.4402x over previous
//
#include <hip/hip_runtime.h>
#include <hip/hip_bf16.h>
#include <math.h>

#define B_ 8
#define N_ 512
#define K_ 16
#define D_ 256
#define F_ 1024
#define H_ 8
#define HD_ 32
#define M_ (B_*N_)      // 4096 rows (b,n)
#define R_ (B_*N_*K_)   // 65536 edge rows
#define RC_ 16384       // edge MLP chunk rows
#define NCH_ (R_/RC_)   // 4 chunks

typedef __bf16 bf16x8 __attribute__((ext_vector_type(8)));
typedef float  f32x4  __attribute__((ext_vector_type(4)));

__device__ inline short bf16s(float f) {
    __hip_bfloat16 h = __float2bfloat16(f);
    return *reinterpret_cast<short*>(&h);
}

// async global->LDS, 16B per lane; lds base must be wave-uniform (dest = base + lane*16)
__device__ __forceinline__ void gload16(const short* g, short* l) {
    __builtin_amdgcn_global_load_lds(
        (const __attribute__((address_space(1))) unsigned int*)g,
        (__attribute__((address_space(3))) unsigned int*)l, 16, 0, 0);
}

// ---------------- weight transpose+convert: W[K][N] f32 -> WT[N][K] bf16 ----
__global__ __launch_bounds__(256) void transposeW(const float* __restrict__ W,
        short* __restrict__ WT, int Kk, int Nn, float scale)
{
    __shared__ float tile[32][33];
    int bx = blockIdx.x;          // along N
    int by = blockIdx.y;          // along K
    int tx = threadIdx.x & 31, ty = threadIdx.x >> 5;   // 32x8
    #pragma unroll
    for (int j = 0; j < 4; ++j) {
        int k = by*32 + ty + j*8;
        tile[ty + j*8][tx] = W[(size_t)k*Nn + bx*32 + tx];
    }
    __syncthreads();
    #pragma unroll
    for (int j = 0; j < 4; ++j) {
        int n = bx*32 + ty + j*8;
        WT[(size_t)n*Kk + by*32 + tx] = bf16s(tile[tx][ty + j*8] * scale);
    }
}

__global__ __launch_bounds__(256) void build_bqkv(const float* __restrict__ bq,
        const float* __restrict__ bk, const float* __restrict__ bv,
        float* __restrict__ bqkv)
{
    int t = blockIdx.x*256 + threadIdx.x;
    if (t >= 768) return;
    float v = (t < 256) ? bq[t]*0.17677669529663687f
            : (t < 512) ? bk[t-256] : bv[t-512];
    bqkv[t] = v;
}

// ---------------- x (N,B,D) f32 -> xtb (B*N, D) bf16 ------------------------
__global__ __launch_bounds__(256) void conv_x(const float* __restrict__ x,
        short* __restrict__ xtb)
{
    int row = blockIdx.x;         // b*N+n
    int d = threadIdx.x;
    int b = row / N_, n = row % N_;
    xtb[(size_t)row*D_ + d] = bf16s(x[((size_t)n*B_ + b)*D_ + d]);
}

// ---------------- means[b,i,k] = mean_d e ----------------------------------
__global__ __launch_bounds__(256) void edge_means(const float* __restrict__ e,
        float* __restrict__ means)
{
    long row = (long)blockIdx.x*4 + (threadIdx.x >> 6);
    int lane = threadIdx.x & 63;
    float4 v = ((const float4*)(e + row*D_))[lane];
    float s = v.x + v.y + v.z + v.w;
    for (int o = 1; o < 64; o <<= 1) s += __shfl_xor(s, o);
    if (lane == 0) means[row] = s * (1.f/D_);
}

__global__ __launch_bounds__(256) void zero4(float4* __restrict__ p, long n4)
{
    long i = (long)blockIdx.x*256 + threadIdx.x;
    if (i < n4) p[i] = make_float4(0.f, 0.f, 0.f, 0.f);
}

// serial per (b,i): numpy last-wins duplicate semantics
__global__ __launch_bounds__(256) void scatter_bias(const int* __restrict__ ei,
        const float* __restrict__ means, float* __restrict__ biasb)
{
    int idx = blockIdx.x*256 + threadIdx.x;   // b*N+i
    if (idx >= B_*N_) return;
    const int* ep = ei + (size_t)idx*K_;
    const float* mp = means + (size_t)idx*K_;
    float* bp = biasb + (size_t)idx*N_;
    for (int k = 0; k < K_; ++k) bp[ep[k]] = mp[k];
}

// ---------------- generic bf16 MFMA GEMM: C = A[M,K] @ BT[N,K]^T + bias -----
// OUTMODE: 0 = f32 Cf, 1 = bf16 Cb, 2 = qkv split (cols<512 -> Cb[.,512], cols>=512 -> vtb transposed)
template<bool GELU, int OUTMODE>
__global__ __launch_bounds__(256) void gemm_bf16(
        const short* __restrict__ A, const short* __restrict__ BT,
        const float* __restrict__ bias, float* __restrict__ Cf,
        short* __restrict__ Cb, short* __restrict__ vtb, int Nn, int Kk)
{
    __shared__ __align__(16) short As[128*32];
    __shared__ __align__(16) short Bs[128*32];
    const int t = threadIdx.x;
    const int lane = t & 63;
    const int wave = t >> 6;
    const int wr = (wave >> 1) * 64;
    const int wc = (wave & 1) * 64;
    const int bm = blockIdx.x, bn = blockIdx.y;
    f32x4 acc[4][4] = {};
    const int srow = lane >> 2;       // staging row within 16-row group
    const int sk   = (lane & 3) * 8;  // staging k offset (8 bf16 = 16B)
    const int fr = lane & 15;
    const int fk = (lane >> 4) * 8;
    for (int k0 = 0; k0 < Kk; k0 += 32) {
        __syncthreads();
        #pragma unroll
        for (int i = 0; i < 2; ++i) {
            const int rb = wave*16 + i*64;
            gload16(A  + (size_t)(bm*128 + rb + srow)*Kk + k0 + sk, &As[rb*32]);
            gload16(BT + (size_t)(bn*128 + rb + srow)*Kk + k0 + sk, &Bs[rb*32]);
        }
        __syncthreads();
        bf16x8 af[4], bfr[4];
        #pragma unroll
        for (int i2 = 0; i2 < 4; ++i2)
            af[i2] = *(const bf16x8*)&As[(wr + i2*16 + fr)*32 + fk];
        #pragma unroll
        for (int n2 = 0; n2 < 4; ++n2)
            bfr[n2] = *(const bf16x8*)&Bs[(wc + n2*16 + fr)*32 + fk];
        #pragma unroll
        for (int i2 = 0; i2 < 4; ++i2)
            #pragma unroll
            for (int n2 = 0; n2 < 4; ++n2)
                acc[i2][n2] = __builtin_amdgcn_mfma_f32_16x16x32_bf16(
                        af[i2], bfr[n2], acc[i2][n2], 0, 0, 0);
    }
    const int fq4 = (lane >> 4) * 4;
    #pragma unroll
    for (int i2 = 0; i2 < 4; ++i2) {
        #pragma unroll
        for (int n2 = 0; n2 < 4; ++n2) {
            const int col = bn*128 + wc + n2*16 + fr;
            const float bv = bias[col];
            if constexpr (OUTMODE == 2) {
                const int rowb = bm*128 + wr + i2*16 + fq4;
                if (col < 512) {
                    #pragma unroll
                    for (int r2 = 0; r2 < 4; ++r2)
                        Cb[(size_t)(rowb + r2)*512 + col] = bf16s(acc[i2][n2][r2] + bv);
                } else {
                    const int b = rowb >> 9, n = rowb & 511;
                    const int dv = col - 512, h = dv >> 5, dh = dv & 31;
                    short4 s4;
                    s4.x = bf16s(acc[i2][n2][0] + bv);
                    s4.y = bf16s(acc[i2][n2][1] + bv);
                    s4.z = bf16s(acc[i2][n2][2] + bv);
                    s4.w = bf16s(acc[i2][n2][3] + bv);
                    *(short4*)&vtb[((size_t)((b*H_ + h)*HD_ + dh))*512 + n] = s4;
                }
            } else {
                #pragma unroll
                for (int r2 = 0; r2 < 4; ++r2) {
                    const int row = bm*128 + wr + i2*16 + fq4 + r2;
                    float v = acc[i2][n2][r2] + bv;
                    if constexpr (GELU) v = 0.5f*v*(1.f + erff(v*0.70710678118654752f));
                    if constexpr (OUTMODE == 0) Cf[(size_t)row*Nn + col] = v;
                    if constexpr (OUTMODE == 1) Cb[(size_t)row*Nn + col] = bf16s(v);
                }
            }
        }
    }
}

// ---------------- GEMM + bias + residual + LayerNorm, 64x256 tile ----------
template<bool TRANSOUT>
__global__ __launch_bounds__(256) void gemm_ln(
        const short* __restrict__ A, const short* __restrict__ BT,
        const float* __restrict__ bias, const float* __restrict__ res,
        const float* __restrict__ g, const float* __restrict__ bt,
        float* __restrict__ out, int Kk)
{
    __shared__ __align__(16) short As[64*32];
    __shared__ __align__(16) short Bs[256*32];
    __shared__ float rs[64][4][2];
    __shared__ float mr[64][2];
    const int t = threadIdx.x;
    const int lane = t & 63;
    const int wave = t >> 6;
    const int wc = wave * 64;
    const int bm = blockIdx.x;
    f32x4 acc[4][4] = {};
    const int srow = lane >> 2;
    const int sk   = (lane & 3) * 8;
    const int fr = lane & 15;
    const int fk = (lane >> 4) * 8;
    for (int k0 = 0; k0 < Kk; k0 += 32) {
        __syncthreads();
        {
            const int rb = wave*16;
            gload16(A + (size_t)(bm*64 + rb + srow)*Kk + k0 + sk, &As[rb*32]);
        }
        #pragma unroll
        for (int i = 0; i < 4; ++i) {
            const int rb = wave*16 + i*64;
            gload16(BT + (size_t)(rb + srow)*Kk + k0 + sk, &Bs[rb*32]);
        }
        __syncthreads();
        bf16x8 af[4], bfr[4];
        #pragma unroll
        for (int i2 = 0; i2 < 4; ++i2)
            af[i2] = *(const bf16x8*)&As[(i2*16 + fr)*32 + fk];
        #pragma unroll
        for (int n2 = 0; n2 < 4; ++n2)
            bfr[n2] = *(const bf16x8*)&Bs[(wc + n2*16 + fr)*32 + fk];
        #pragma unroll
        for (int i2 = 0; i2 < 4; ++i2)
            #pragma unroll
            for (int n2 = 0; n2 < 4; ++n2)
                acc[i2][n2] = __builtin_amdgcn_mfma_f32_16x16x32_bf16(
                        af[i2], bfr[n2], acc[i2][n2], 0, 0, 0);
    }
    const int fq4 = (lane >> 4) * 4;
    float ps[4][4] = {}, pq[4][4] = {};
    #pragma unroll
    for (int i2 = 0; i2 < 4; ++i2) {
        #pragma unroll
        for (int n2 = 0; n2 < 4; ++n2) {
            const int c = wc + n2*16 + fr;
            const float bv = bias[c];
            #pragma unroll
            for (int r2 = 0; r2 < 4; ++r2) {
                const int row = i2*16 + fq4 + r2;
                const size_t grow = (size_t)bm*64 + row;
                float v = acc[i2][n2][r2] + bv + res[grow*256 + c];
                acc[i2][n2][r2] = v;
                ps[i2][r2] += v;
                pq[i2][r2] += v*v;
            }
        }
    }
    #pragma unroll
    for (int i2 = 0; i2 < 4; ++i2)
        #pragma unroll
        for (int r2 = 0; r2 < 4; ++r2)
            #pragma unroll
            for (int o = 1; o < 16; o <<= 1) {
                ps[i2][r2] += __shfl_xor(ps[i2][r2], o);
                pq[i2][r2] += __shfl_xor(pq[i2][r2], o);
            }
    if ((lane & 15) == 0) {
        #pragma unroll
        for (int i2 = 0; i2 < 4; ++i2)
            #pragma unroll
            for (int r2 = 0; r2 < 4; ++r2) {
                const int row = i2*16 + fq4 + r2;
                rs[row][wave][0] = ps[i2][r2];
                rs[row][wave][1] = pq[i2][r2];
            }
    }
    __syncthreads();
    if (t < 64) {
        float S = 0.f, Q = 0.f;
        #pragma unroll
        for (int w = 0; w < 4; ++w) { S += rs[t][w][0]; Q += rs[t][w][1]; }
        const float mean = S * (1.f/D_);
        mr[t][0] = mean;
        mr[t][1] = rsqrtf(Q * (1.f/D_) - mean*mean + 1e-5f);
    }
    __syncthreads();
    #pragma unroll
    for (int i2 = 0; i2 < 4; ++i2) {
        #pragma unroll
        for (int n2 = 0; n2 < 4; ++n2) {
            const int c = wc + n2*16 + fr;
            const float gv = g[c], bv2 = bt[c];
            #pragma unroll
            for (int r2 = 0; r2 < 4; ++r2) {
                const int row = i2*16 + fq4 + r2;
                const size_t grow = (size_t)bm*64 + row;
                const float o = (acc[i2][n2][r2] - mr[row][0])*mr[row][1]*gv + bv2;
                if constexpr (TRANSOUT) {
                    const int bb = (int)(grow >> 9), nn = (int)(grow & 511);
                    out[((size_t)nn*B_ + bb)*D_ + c] = o;
                } else {
                    out[grow*256 + c] = o;
                }
            }
        }
    }
}

// ---------------- attn scores: P=exp(QK^T+bias) bf16 (unnormalized) + rowsum
__global__ __launch_bounds__(256) void attn_score(const short* __restrict__ qkb,
        const float* __restrict__ biasb, short* __restrict__ P,
        float* __restrict__ rowsum)
{
    __shared__ __align__(16) short Qs[128*32];
    __shared__ __align__(16) short Ks[128*32];
    __shared__ float rs[128][2];
    const int it = blockIdx.x, bh = blockIdx.y;
    const int b = bh >> 3, h = bh & 7;
    const int t = threadIdx.x;
    const int lane = t & 63;
    const int wave = t >> 6;
    const int wr = (wave >> 1) * 64;
    const int wc = (wave & 1) * 64;
    const int srow = lane >> 2;
    const int sk   = (lane & 3) * 8;
    const int fr = lane & 15;
    const int fk = (lane >> 4) * 8;
    const int fq4 = (lane >> 4) * 4;
    #pragma unroll
    for (int i = 0; i < 2; ++i) {
        const int rb = wave*16 + i*64;
        gload16(qkb + (size_t)(b*N_ + it*128 + rb + srow)*512 + h*HD_ + sk, &Qs[rb*32]);
    }
    float rsum[4][4] = {};
    const float LOG2E = 1.4426950408889634f;
    for (int jt = 0; jt < 4; ++jt) {
        __syncthreads();
        #pragma unroll
        for (int i = 0; i < 2; ++i) {
            const int rb = wave*16 + i*64;
            gload16(qkb + (size_t)(b*N_ + jt*128 + rb + srow)*512 + 256 + h*HD_ + sk, &Ks[rb*32]);
        }
        __syncthreads();
        bf16x8 aq[4], bk[4];
        #pragma unroll
        for (int i2 = 0; i2 < 4; ++i2)
            aq[i2] = *(const bf16x8*)&Qs[(wr + i2*16 + fr)*32 + fk];
        #pragma unroll
        for (int n2 = 0; n2 < 4; ++n2)
            bk[n2] = *(const bf16x8*)&Ks[(wc + n2*16 + fr)*32 + fk];
        #pragma unroll
        for (int i2 = 0; i2 < 4; ++i2) {
            #pragma unroll
            for (int n2 = 0; n2 < 4; ++n2) {
                f32x4 z = {0.f, 0.f, 0.f, 0.f};
                f32x4 s = __builtin_amdgcn_mfma_f32_16x16x32_bf16(aq[i2], bk[n2], z, 0, 0, 0);
                const int jg = jt*128 + wc + n2*16 + fr;
                #pragma unroll
                for (int r2 = 0; r2 < 4; ++r2) {
                    const int ig = it*128 + wr + i2*16 + fq4 + r2;
                    const float l = s[r2] + biasb[((size_t)b*N_ + ig)*N_ + jg];
                    const float p = exp2f(fminf(l, 80.f) * LOG2E);
                    rsum[i2][r2] += p;
                    P[((size_t)bh*N_ + ig)*N_ + jg] = bf16s(p);
                }
            }
        }
    }
    #pragma unroll
    for (int i2 = 0; i2 < 4; ++i2)
        #pragma unroll
        for (int r2 = 0; r2 < 4; ++r2)
            #pragma unroll
            for (int o = 1; o < 16; o <<= 1)
                rsum[i2][r2] += __shfl_xor(rsum[i2][r2], o);
    if ((lane & 15) == 0) {
        #pragma unroll
        for (int i2 = 0; i2 < 4; ++i2)
            #pragma unroll
            for (int r2 = 0; r2 < 4; ++r2)
                rs[wr + i2*16 + fq4 + r2][wave & 1] = rsum[i2][r2];
    }
    __syncthreads();
    if (t < 128)
        rowsum[(size_t)bh*N_ + it*128 + t] = rs[t][0] + rs[t][1];
}

// ---------------- head mean: wmean[b,i,j] = (1/H) sum_h P/rowsum ------------
__global__ __launch_bounds__(256) void head_mean(const short* __restrict__ P,
        const float* __restrict__ rowsum, float* __restrict__ wmean)
{
    const int bi = blockIdx.x;         // b*N + i
    const int b = bi >> 9, i = bi & 511;
    float rinv[H_];
    #pragma unroll
    for (int h = 0; h < H_; ++h)
        rinv[h] = 1.f / rowsum[(size_t)(b*H_ + h)*N_ + i];
    const int t = threadIdx.x;
    const __hip_bfloat16* Pb = (const __hip_bfloat16*)P;
    #pragma unroll
    for (int jj = 0; jj < 2; ++jj) {
        const int j = t + jj*256;
        float s = 0.f;
        #pragma unroll
        for (int h = 0; h < H_; ++h)
            s += __bfloat162float(Pb[((size_t)(b*H_ + h)*N_ + i)*N_ + j]) * rinv[h];
        wmean[((size_t)b*N_ + i)*N_ + j] = s * (1.f/H_);
    }
}

// ---------------- PV: actx[b,n,h*32+dh] = (P@V^T)/rowsum (bf16) -------------
__global__ __launch_bounds__(256) void attn_pv(const short* __restrict__ P,
        const short* __restrict__ vtb, const float* __restrict__ rowsum,
        short* __restrict__ actx)
{
    __shared__ __align__(16) short Ps[128*64];
    __shared__ __align__(16) short Vs[32*64];
    const int it = blockIdx.x, bh = blockIdx.y;
    const int b = bh >> 3, h = bh & 7;
    const int t = threadIdx.x;
    const int lane = t & 63;
    const int wave = t >> 6;
    const int wr = wave * 32;
    const int srow8 = lane >> 3;
    const int sk8   = (lane & 7) * 8;
    const int fr = lane & 15;
    const int fk = (lane >> 4) * 8;
    const int fq4 = (lane >> 4) * 4;
    f32x4 acc[2][2] = {};
    for (int mt = 0; mt < 8; ++mt) {
        __syncthreads();
        #pragma unroll
        for (int i = 0; i < 4; ++i) {
            const int rb = wave*32 + i*8;
            gload16(P + ((size_t)bh*N_ + it*128 + rb + srow8)*512 + mt*64 + sk8, &Ps[rb*64]);
        }
        {
            const int rb = wave*8;
            gload16(vtb + ((size_t)bh*HD_ + rb + srow8)*512 + mt*64 + sk8, &Vs[rb*64]);
        }
        __syncthreads();
        #pragma unroll
        for (int kk = 0; kk < 2; ++kk) {
            bf16x8 af[2], bfv[2];
            #pragma unroll
            for (int i2 = 0; i2 < 2; ++i2)
                af[i2] = *(const bf16x8*)&Ps[(wr + i2*16 + fr)*64 + kk*32 + fk];
            #pragma unroll
            for (int n2 = 0; n2 < 2; ++n2)
                bfv[n2] = *(const bf16x8*)&Vs[(n2*16 + fr)*64 + kk*32 + fk];
            #pragma unroll
            for (int i2 = 0; i2 < 2; ++i2)
                #pragma unroll
                for (int n2 = 0; n2 < 2; ++n2)
                    acc[i2][n2] = __builtin_amdgcn_mfma_f32_16x16x32_bf16(
                            af[i2], bfv[n2], acc[i2][n2], 0, 0, 0);
        }
    }
    #pragma unroll
    for (int i2 = 0; i2 < 2; ++i2) {
        #pragma unroll
        for (int r2 = 0; r2 < 4; ++r2) {
            const int row = wr + i2*16 + fq4 + r2;
            const float inv = 1.f / rowsum[(size_t)bh*N_ + it*128 + row];
            #pragma unroll
            for (int n2 = 0; n2 < 2; ++n2) {
                actx[((size_t)b*N_ + it*128 + row)*D_ + h*HD_ + n2*16 + fr]
                    = bf16s(acc[i2][n2][r2] * inv);
            }
        }
    }
}

// ---------------- LN helpers (wave per row of 256) ---------------------------
__device__ inline void ln_core(float v[4], int lane, const float* __restrict__ g,
        const float* __restrict__ bt, float out[4])
{
    float s  = v[0] + v[1] + v[2] + v[3];
    float sq = v[0]*v[0] + v[1]*v[1] + v[2]*v[2] + v[3]*v[3];
    for (int o = 1; o < 64; o <<= 1) { s += __shfl_xor(s, o); sq += __shfl_xor(sq, o); }
    float mean = s * (1.f/D_);
    float rstd = rsqrtf(sq * (1.f/D_) - mean*mean + 1e-5f);
    const float4 gv = *(const float4*)(g  + lane*4);
    const float4 bv = *(const float4*)(bt + lane*4);
    out[0] = (v[0]-mean)*rstd*gv.x + bv.x;
    out[1] = (v[1]-mean)*rstd*gv.y + bv.y;
    out[2] = (v[2]-mean)*rstd*gv.z + bv.z;
    out[3] = (v[3]-mean)*rstd*gv.w + bv.w;
}

// xn = LN(x^T + aout); writes f32 + bf16
__global__ __launch_bounds__(256) void ln_xn(const float* __restrict__ x,
        const float* __restrict__ aout, const float* __restrict__ g,
        const float* __restrict__ bt, float* __restrict__ xn, short* __restrict__ xnb)
{
    int row = blockIdx.x*4 + (threadIdx.x >> 6);
    int lane = threadIdx.x & 63;
    int b = row / N_, n = row % N_;
    const float4 xv = *(const float4*)(x + ((size_t)n*B_ + b)*D_ + lane*4);
    const float4 av = *(const float4*)(aout + (size_t)row*D_ + lane*4);
    float v[4] = {xv.x+av.x, xv.y+av.y, xv.z+av.z, xv.w+av.w};
    float o[4];
    ln_core(v, lane, g, bt, o);
    *(float4*)(xn + (size_t)row*D_ + lane*4) = make_float4(o[0], o[1], o[2], o[3]);
    short4 s4; s4.x = bf16s(o[0]); s4.y = bf16s(o[1]); s4.z = bf16s(o[2]); s4.w = bf16s(o[3]);
    *(short4*)(xnb + (size_t)row*D_ + lane*4) = s4;
}

// e2 = LN(e + w*gathered); writes f32 (d_out region) + bf16
__global__ __launch_bounds__(256) void edge_update(const float* __restrict__ e,
        const float* __restrict__ x, const int* __restrict__ ei,
        const float* __restrict__ wmean, const float* __restrict__ g,
        const float* __restrict__ bt, float* __restrict__ e2f, short* __restrict__ e2b)
{
    long row = (long)blockIdx.x*4 + (threadIdx.x >> 6);   // b*N*K + i*K + k
    int lane = threadIdx.x & 63;
    long bi = row >> 4;          // / K_
    long b = bi / N_; int i = (int)(bi % N_);
    int ej = ei[row];
    float w = wmean[((size_t)b*N_ + ej)*N_ + i];
    const float4 ev = *(const float4*)(e + row*D_ + lane*4);
    const float4 xv = *(const float4*)(x + ((size_t)ej*B_ + b)*D_ + lane*4);
    float v[4] = {ev.x + w*xv.x, ev.y + w*xv.y, ev.z + w*xv.z, ev.w + w*xv.w};
    float o[4];
    ln_core(v, lane, g, bt, o);
    *(float4*)(e2f + row*D_ + lane*4) = make_float4(o[0], o[1], o[2], o[3]);
    short4 s4; s4.x = bf16s(o[0]); s4.y = bf16s(o[1]); s4.z = bf16s(o[2]); s4.w = bf16s(o[3]);
    *(short4*)(e2b + row*D_ + lane*4) = s4;
}

// ============================================================================
extern "C" void kernel_launch(void* const* d_in, const int* in_sizes, int n_in,
                              void* d_out, int out_size, void* d_ws, size_t ws_size,
                              hipStream_t stream)
{
    (void)in_sizes; (void)n_in; (void)out_size; (void)ws_size;
    const float* x    = (const float*)d_in[0];
    const float* e    = (const float*)d_in[1];
    const int*   ei   = (const int*)d_in[2];
    const float* Wq   = (const float*)d_in[3];
    const float* bq   = (const float*)d_in[4];
    const float* Wk   = (const float*)d_in[5];
    const float* bk   = (const float*)d_in[6];
    const float* Wv   = (const float*)d_in[7];
    const float* bv   = (const float*)d_in[8];
    const float* Wo   = (const float*)d_in[9];
    const float* bo   = (const float*)d_in[10];
    const float* nW1  = (const float*)d_in[11];
    const float* nb1  = (const float*)d_in[12];
    const float* nW2  = (const float*)d_in[13];
    const float* nb2  = (const float*)d_in[14];
    const float* eW1  = (const float*)d_in[15];
    const float* eb1  = (const float*)d_in[16];
    const float* eW2  = (const float*)d_in[17];
    const float* eb2  = (const float*)d_in[18];
    const float* na_g = (const float*)d_in[19];
    const float* na_b = (const float*)d_in[20];
    const float* ea_g = (const float*)d_in[21];
    const float* ea_b = (const float*)d_in[22];
    const float* nf_g = (const float*)d_in[23];
    const float* nf_b = (const float*)d_in[24];
    const float* ef_g = (const float*)d_in[25];
    const float* ef_b = (const float*)d_in[26];

    float* out1 = (float*)d_out;                       // (N,B,D)
    float* e2f  = out1 + (size_t)N_*B_*D_;             // (B,N,K,D) — e2 intermediate + final

    char* wp = (char*)d_ws;
    auto alloc = [&](size_t bytes) -> char* {
        char* p = wp; wp += (bytes + 255) & ~(size_t)255; return p;
    };
    short* xtb    = (short*)alloc((size_t)M_*D_*2);
    short* WqkvT  = (short*)alloc((size_t)768*D_*2);
    float* bqkv   = (float*)alloc(768*4);
    short* WoT    = (short*)alloc((size_t)D_*D_*2);
    short* nW1T   = (short*)alloc((size_t)F_*D_*2);
    short* nW2T   = (short*)alloc((size_t)D_*F_*2);
    short* eW1T   = (short*)alloc((size_t)F_*D_*2);
    short* eW2T   = (short*)alloc((size_t)D_*F_*2);
    float* means  = (float*)alloc((size_t)R_*4);
    float* biasb  = (float*)alloc((size_t)B_*N_*N_*4);
    short* qkb    = (short*)alloc((size_t)M_*512*2);
    short* vtb    = (short*)alloc((size_t)B_*H_*HD_*N_*2);
    short* Pun    = (short*)alloc((size_t)B_*H_*N_*N_*2);
    float* rowsum = (float*)alloc((size_t)B_*H_*N_*4);
    float* wmean  = (float*)alloc((size_t)B_*N_*N_*4);
    short* actx   = (short*)alloc((size_t)M_*D_*2);
    float* aout   = (float*)alloc((size_t)M_*D_*4);
    float* xn     = (float*)alloc((size_t)M_*D_*4);
    short* xnb    = (short*)alloc((size_t)M_*D_*2);
    short* nhid   = (short*)alloc((size_t)M_*F_*2);
    short* e2b    = (short*)alloc((size_t)R_*D_*2);
    short* ehid   = (short*)alloc((size_t)RC_*F_*2);

    // ---- weight prep ----
    transposeW<<<dim3(D_/32, D_/32), 256, 0, stream>>>(Wq, WqkvT,           D_, D_, 0.17677669529663687f);
    transposeW<<<dim3(D_/32, D_/32), 256, 0, stream>>>(Wk, WqkvT + 256*D_,  D_, D_, 1.f);
    transposeW<<<dim3(D_/32, D_/32), 256, 0, stream>>>(Wv, WqkvT + 512*D_,  D_, D_, 1.f);
    build_bqkv<<<3, 256, 0, stream>>>(bq, bk, bv, bqkv);
    transposeW<<<dim3(D_/32, D_/32), 256, 0, stream>>>(Wo, WoT, D_, D_, 1.f);
    transposeW<<<dim3(F_/32, D_/32), 256, 0, stream>>>(nW1, nW1T, D_, F_, 1.f);
    transposeW<<<dim3(D_/32, F_/32), 256, 0, stream>>>(nW2, nW2T, F_, D_, 1.f);
    transposeW<<<dim3(F_/32, D_/32), 256, 0, stream>>>(eW1, eW1T, D_, F_, 1.f);
    transposeW<<<dim3(D_/32, F_/32), 256, 0, stream>>>(eW2, eW2T, F_, D_, 1.f);
    conv_x<<<M_, 256, 0, stream>>>(x, xtb);

    // ---- attn bias ----
    edge_means<<<R_/4, 256, 0, stream>>>(e, means);
    zero4<<<2048, 256, 0, stream>>>((float4*)biasb, (long)B_*N_*N_/4);
    scatter_bias<<<(M_ + 255)/256, 256, 0, stream>>>(ei, means, biasb);

    // ---- QKV (fused, q-scale folded into Wq/bq) ----
    gemm_bf16<false,2><<<dim3(M_/128, 768/128), 256, 0, stream>>>(
            xtb, WqkvT, bqkv, nullptr, qkb, vtb, 768, D_);

    // ---- attention ----
    attn_score<<<dim3(N_/128, B_*H_), 256, 0, stream>>>(qkb, biasb, Pun, rowsum);
    head_mean<<<B_*N_, 256, 0, stream>>>(Pun, rowsum, wmean);
    attn_pv<<<dim3(N_/128, B_*H_), 256, 0, stream>>>(Pun, vtb, rowsum, actx);
    gemm_bf16<false,0><<<dim3(M_/128, D_/128), 256, 0, stream>>>(
            actx, WoT, bo, aout, nullptr, nullptr, D_, D_);

    // ---- node path ----
    ln_xn<<<M_/4, 256, 0, stream>>>(x, aout, na_g, na_b, xn, xnb);
    gemm_bf16<true,1><<<dim3(M_/128, F_/128), 256, 0, stream>>>(
            xnb, nW1T, nb1, nullptr, nhid, nullptr, F_, D_);
    gemm_ln<true><<<M_/64, 256, 0, stream>>>(
            nhid, nW2T, nb2, xn, nf_g, nf_b, out1, F_);

    // ---- edge path ----
    edge_update<<<R_/4, 256, 0, stream>>>(e, x, ei, wmean, ea_g, ea_b, e2f, e2b);
    for (int c = 0; c < NCH_; ++c) {
        gemm_bf16<true,1><<<dim3(RC_/128, F_/128), 256, 0, stream>>>(
                e2b + (size_t)c*RC_*D_, eW1T, eb1, nullptr, ehid, nullptr, F_, D_);
        gemm_ln<false><<<RC_/64, 256, 0, stream>>>(
                ehid, eW2T, eb2, e2f + (size_t)c*RC_*D_, ef_g, ef_b,
                e2f + (size_t)c*RC_*D_, F_);
    }
}

// Round 3
// 428.325 us; speedup vs baseline: 1.6204x; 1.1251x over previous
//
#include <hip/hip_runtime.h>
#include <hip/hip_bf16.h>
#include <math.h>

#define B_ 8
#define N_ 512
#define K_ 16
#define D_ 256
#define F_ 1024
#define H_ 8
#define HD_ 32
#define M_ (B_*N_)      // 4096 rows (b,n)
#define R_ (B_*N_*K_)   // 65536 edge rows
#define RC_ 16384       // edge MLP chunk rows
#define NCH_ (R_/RC_)   // 4 chunks

typedef __bf16 bf16x8 __attribute__((ext_vector_type(8)));
typedef float  f32x4  __attribute__((ext_vector_type(4)));

__device__ inline short bf16s(float f) {
    __hip_bfloat16 h = __float2bfloat16(f);
    return *reinterpret_cast<short*>(&h);
}
__device__ inline float b2f(short s) {
    union { float f; unsigned u; } v; v.u = ((unsigned)(unsigned short)s) << 16; return v.f;
}

// async global->LDS, 16B per lane; lds base must be wave-uniform (dest = base + lane*16)
__device__ __forceinline__ void gload16(const short* g, short* l) {
    __builtin_amdgcn_global_load_lds(
        (const __attribute__((address_space(1))) unsigned int*)g,
        (__attribute__((address_space(3))) unsigned int*)l, 16, 0, 0);
}

// ---------------- weight transpose+convert: W[K][N] f32 -> WT[N][K] bf16 ----
__global__ __launch_bounds__(256) void transposeW(const float* __restrict__ W,
        short* __restrict__ WT, int Kk, int Nn, float scale)
{
    __shared__ float tile[32][33];
    int bx = blockIdx.x;          // along N
    int by = blockIdx.y;          // along K
    int tx = threadIdx.x & 31, ty = threadIdx.x >> 5;   // 32x8
    #pragma unroll
    for (int j = 0; j < 4; ++j) {
        int k = by*32 + ty + j*8;
        tile[ty + j*8][tx] = W[(size_t)k*Nn + bx*32 + tx];
    }
    __syncthreads();
    #pragma unroll
    for (int j = 0; j < 4; ++j) {
        int n = bx*32 + ty + j*8;
        WT[(size_t)n*Kk + by*32 + tx] = bf16s(tile[tx][ty + j*8] * scale);
    }
}

__global__ __launch_bounds__(256) void build_bqkv(const float* __restrict__ bq,
        const float* __restrict__ bk, const float* __restrict__ bv,
        float* __restrict__ bqkv)
{
    int t = blockIdx.x*256 + threadIdx.x;
    if (t >= 768) return;
    float v = (t < 256) ? bq[t]*0.17677669529663687f
            : (t < 512) ? bk[t-256] : bv[t-512];
    bqkv[t] = v;
}

// ---------------- x (N,B,D) f32 -> xtb (B*N, D) bf16 ------------------------
__global__ __launch_bounds__(256) void conv_x(const float* __restrict__ x,
        short* __restrict__ xtb)
{
    int row = blockIdx.x;         // b*N+n
    int d = threadIdx.x;
    int b = row / N_, n = row % N_;
    xtb[(size_t)row*D_ + d] = bf16s(x[((size_t)n*B_ + b)*D_ + d]);
}

// ---------------- means[b,i,k] = mean_d e ----------------------------------
__global__ __launch_bounds__(256) void edge_means(const float* __restrict__ e,
        float* __restrict__ means)
{
    long row = (long)blockIdx.x*4 + (threadIdx.x >> 6);
    int lane = threadIdx.x & 63;
    float4 v = ((const float4*)(e + row*D_))[lane];
    float s = v.x + v.y + v.z + v.w;
    for (int o = 1; o < 64; o <<= 1) s += __shfl_xor(s, o);
    if (lane == 0) means[row] = s * (1.f/D_);
}

__global__ __launch_bounds__(256) void zero4(float4* __restrict__ p, long n4)
{
    long i = (long)blockIdx.x*256 + threadIdx.x;
    if (i < n4) p[i] = make_float4(0.f, 0.f, 0.f, 0.f);
}

// serial per (b,i): numpy last-wins duplicate semantics
__global__ __launch_bounds__(256) void scatter_bias(const int* __restrict__ ei,
        const float* __restrict__ means, float* __restrict__ biasb)
{
    int idx = blockIdx.x*256 + threadIdx.x;   // b*N+i
    if (idx >= B_*N_) return;
    const int* ep = ei + (size_t)idx*K_;
    const float* mp = means + (size_t)idx*K_;
    float* bp = biasb + (size_t)idx*N_;
    for (int k = 0; k < K_; ++k) bp[ep[k]] = mp[k];
}

// ---------------- generic bf16 MFMA GEMM: C = A[M,K] @ BT[N,K]^T + bias -----
// OUTMODE: 0 = f32 Cf, 1 = bf16 Cb, 2 = qkv split (cols<512 -> Cb[.,512], cols>=512 -> vtb transposed)
template<bool GELU, int OUTMODE>
__global__ __launch_bounds__(256) void gemm_bf16(
        const short* __restrict__ A, const short* __restrict__ BT,
        const float* __restrict__ bias, float* __restrict__ Cf,
        short* __restrict__ Cb, short* __restrict__ vtb, int Nn, int Kk)
{
    __shared__ __align__(16) short As[128*32];
    __shared__ __align__(16) short Bs[128*32];
    const int t = threadIdx.x;
    const int lane = t & 63;
    const int wave = t >> 6;
    const int wr = (wave >> 1) * 64;
    const int wc = (wave & 1) * 64;
    const int bm = blockIdx.x, bn = blockIdx.y;
    f32x4 acc[4][4] = {};
    const int srow = lane >> 2;       // staging row within 16-row group
    const int sk   = (lane & 3) * 8;  // staging k offset (8 bf16 = 16B)
    const int fr = lane & 15;
    const int fk = (lane >> 4) * 8;
    for (int k0 = 0; k0 < Kk; k0 += 32) {
        __syncthreads();
        #pragma unroll
        for (int i = 0; i < 2; ++i) {
            const int rb = wave*16 + i*64;
            gload16(A  + (size_t)(bm*128 + rb + srow)*Kk + k0 + sk, &As[rb*32]);
            gload16(BT + (size_t)(bn*128 + rb + srow)*Kk + k0 + sk, &Bs[rb*32]);
        }
        __syncthreads();
        bf16x8 af[4], bfr[4];
        #pragma unroll
        for (int i2 = 0; i2 < 4; ++i2)
            af[i2] = *(const bf16x8*)&As[(wr + i2*16 + fr)*32 + fk];
        #pragma unroll
        for (int n2 = 0; n2 < 4; ++n2)
            bfr[n2] = *(const bf16x8*)&Bs[(wc + n2*16 + fr)*32 + fk];
        #pragma unroll
        for (int i2 = 0; i2 < 4; ++i2)
            #pragma unroll
            for (int n2 = 0; n2 < 4; ++n2)
                acc[i2][n2] = __builtin_amdgcn_mfma_f32_16x16x32_bf16(
                        af[i2], bfr[n2], acc[i2][n2], 0, 0, 0);
    }
    const int fq4 = (lane >> 4) * 4;
    #pragma unroll
    for (int i2 = 0; i2 < 4; ++i2) {
        #pragma unroll
        for (int n2 = 0; n2 < 4; ++n2) {
            const int col = bn*128 + wc + n2*16 + fr;
            const float bv = bias[col];
            if constexpr (OUTMODE == 2) {
                const int rowb = bm*128 + wr + i2*16 + fq4;
                if (col < 512) {
                    #pragma unroll
                    for (int r2 = 0; r2 < 4; ++r2)
                        Cb[(size_t)(rowb + r2)*512 + col] = bf16s(acc[i2][n2][r2] + bv);
                } else {
                    const int b = rowb >> 9, n = rowb & 511;
                    const int dv = col - 512, h = dv >> 5, dh = dv & 31;
                    short4 s4;
                    s4.x = bf16s(acc[i2][n2][0] + bv);
                    s4.y = bf16s(acc[i2][n2][1] + bv);
                    s4.z = bf16s(acc[i2][n2][2] + bv);
                    s4.w = bf16s(acc[i2][n2][3] + bv);
                    *(short4*)&vtb[((size_t)((b*H_ + h)*HD_ + dh))*512 + n] = s4;
                }
            } else {
                #pragma unroll
                for (int r2 = 0; r2 < 4; ++r2) {
                    const int row = bm*128 + wr + i2*16 + fq4 + r2;
                    float v = acc[i2][n2][r2] + bv;
                    if constexpr (GELU) v = 0.5f*v*(1.f + erff(v*0.70710678118654752f));
                    if constexpr (OUTMODE == 0) Cf[(size_t)row*Nn + col] = v;
                    if constexpr (OUTMODE == 1) Cb[(size_t)row*Nn + col] = bf16s(v);
                }
            }
        }
    }
}

// ---------------- GEMM + bias + residual + LayerNorm, 64x256 tile ----------
template<bool TRANSOUT>
__global__ __launch_bounds__(256) void gemm_ln(
        const short* __restrict__ A, const short* __restrict__ BT,
        const float* __restrict__ bias, const float* __restrict__ res,
        const float* __restrict__ g, const float* __restrict__ bt,
        float* __restrict__ out, int Kk)
{
    __shared__ __align__(16) short As[64*32];
    __shared__ __align__(16) short Bs[256*32];
    __shared__ float rs[64][4][2];
    __shared__ float mr[64][2];
    const int t = threadIdx.x;
    const int lane = t & 63;
    const int wave = t >> 6;
    const int wc = wave * 64;
    const int bm = blockIdx.x;
    f32x4 acc[4][4] = {};
    const int srow = lane >> 2;
    const int sk   = (lane & 3) * 8;
    const int fr = lane & 15;
    const int fk = (lane >> 4) * 8;
    for (int k0 = 0; k0 < Kk; k0 += 32) {
        __syncthreads();
        {
            const int rb = wave*16;
            gload16(A + (size_t)(bm*64 + rb + srow)*Kk + k0 + sk, &As[rb*32]);
        }
        #pragma unroll
        for (int i = 0; i < 4; ++i) {
            const int rb = wave*16 + i*64;
            gload16(BT + (size_t)(rb + srow)*Kk + k0 + sk, &Bs[rb*32]);
        }
        __syncthreads();
        bf16x8 af[4], bfr[4];
        #pragma unroll
        for (int i2 = 0; i2 < 4; ++i2)
            af[i2] = *(const bf16x8*)&As[(i2*16 + fr)*32 + fk];
        #pragma unroll
        for (int n2 = 0; n2 < 4; ++n2)
            bfr[n2] = *(const bf16x8*)&Bs[(wc + n2*16 + fr)*32 + fk];
        #pragma unroll
        for (int i2 = 0; i2 < 4; ++i2)
            #pragma unroll
            for (int n2 = 0; n2 < 4; ++n2)
                acc[i2][n2] = __builtin_amdgcn_mfma_f32_16x16x32_bf16(
                        af[i2], bfr[n2], acc[i2][n2], 0, 0, 0);
    }
    const int fq4 = (lane >> 4) * 4;
    float ps[4][4] = {}, pq[4][4] = {};
    #pragma unroll
    for (int i2 = 0; i2 < 4; ++i2) {
        #pragma unroll
        for (int n2 = 0; n2 < 4; ++n2) {
            const int c = wc + n2*16 + fr;
            const float bv = bias[c];
            #pragma unroll
            for (int r2 = 0; r2 < 4; ++r2) {
                const int row = i2*16 + fq4 + r2;
                const size_t grow = (size_t)bm*64 + row;
                float v = acc[i2][n2][r2] + bv + res[grow*256 + c];
                acc[i2][n2][r2] = v;
                ps[i2][r2] += v;
                pq[i2][r2] += v*v;
            }
        }
    }
    #pragma unroll
    for (int i2 = 0; i2 < 4; ++i2)
        #pragma unroll
        for (int r2 = 0; r2 < 4; ++r2)
            #pragma unroll
            for (int o = 1; o < 16; o <<= 1) {
                ps[i2][r2] += __shfl_xor(ps[i2][r2], o);
                pq[i2][r2] += __shfl_xor(pq[i2][r2], o);
            }
    if ((lane & 15) == 0) {
        #pragma unroll
        for (int i2 = 0; i2 < 4; ++i2)
            #pragma unroll
            for (int r2 = 0; r2 < 4; ++r2) {
                const int row = i2*16 + fq4 + r2;
                rs[row][wave][0] = ps[i2][r2];
                rs[row][wave][1] = pq[i2][r2];
            }
    }
    __syncthreads();
    if (t < 64) {
        float S = 0.f, Q = 0.f;
        #pragma unroll
        for (int w = 0; w < 4; ++w) { S += rs[t][w][0]; Q += rs[t][w][1]; }
        const float mean = S * (1.f/D_);
        mr[t][0] = mean;
        mr[t][1] = rsqrtf(Q * (1.f/D_) - mean*mean + 1e-5f);
    }
    __syncthreads();
    #pragma unroll
    for (int i2 = 0; i2 < 4; ++i2) {
        #pragma unroll
        for (int n2 = 0; n2 < 4; ++n2) {
            const int c = wc + n2*16 + fr;
            const float gv = g[c], bv2 = bt[c];
            #pragma unroll
            for (int r2 = 0; r2 < 4; ++r2) {
                const int row = i2*16 + fq4 + r2;
                const size_t grow = (size_t)bm*64 + row;
                const float o = (acc[i2][n2][r2] - mr[row][0])*mr[row][1]*gv + bv2;
                if constexpr (TRANSOUT) {
                    const int bb = (int)(grow >> 9), nn = (int)(grow & 511);
                    out[((size_t)nn*B_ + bb)*D_ + c] = o;
                } else {
                    out[grow*256 + c] = o;
                }
            }
        }
    }
}

// ---------------- fused flash attention: QK^T+bias -> exp -> PV -------------
// grid (N/128, B*H). Never materializes P in HBM; writes rowsum + actx.
__global__ __launch_bounds__(256) void attn_fused(const short* __restrict__ qkb,
        const short* __restrict__ vtb, const float* __restrict__ biasb,
        float* __restrict__ rowsum, short* __restrict__ actx)
{
    __shared__ __align__(16) short Qs[128*32];
    __shared__ __align__(16) short Ks[128*32];
    __shared__ __align__(16) short Vs[32*128];     // [dh][j], source-pre-swizzled
    __shared__ __align__(16) short Ps[128*128];    // XOR-swizzled bf16 P tile
    const int it = blockIdx.x, bh = blockIdx.y;
    const int b = bh >> 3, h = bh & 7;
    const int t = threadIdx.x;
    const int lane = t & 63;
    const int wave = t >> 6;
    const int wr0 = wave * 32;
    const int srow = lane >> 2;        // staging: 16 rows x 64B
    const int sk   = (lane & 3) * 8;
    const int srow8 = lane >> 4;       // staging: 4 rows x 256B
    const int ck16  = lane & 15;       // 16B chunk index within 128-col row
    const int fr = lane & 15;
    const int fk = (lane >> 4) * 8;
    const int fq4 = (lane >> 4) * 4;
    const int I0 = it * 128;
    // stage Q once
    #pragma unroll
    for (int i = 0; i < 2; ++i) {
        const int rb = wave*16 + i*64;
        gload16(qkb + (size_t)(b*N_ + I0 + rb + srow)*512 + h*HD_ + sk, &Qs[rb*32]);
    }
    float rsum[2][4] = {};
    f32x4 apv[2][2] = {};
    const float LOG2E = 1.4426950408889634f;
    for (int jt = 0; jt < 4; ++jt) {
        const int J0 = jt * 128;
        __syncthreads();   // prev PV reads done (and Q staged, first iter)
        #pragma unroll
        for (int i = 0; i < 2; ++i) {
            const int rb = wave*16 + i*64;
            gload16(qkb + (size_t)(b*N_ + J0 + rb + srow)*512 + 256 + h*HD_ + sk, &Ks[rb*32]);
        }
        #pragma unroll
        for (int i = 0; i < 2; ++i) {
            const int db = wave*8 + i*4;
            const int dh = db + srow8;
            // pre-swizzled source so LDS(dh, c') = V[dh][c' ^ (dh&7)]
            gload16(vtb + ((size_t)bh*HD_ + dh)*512 + J0 + ((ck16 ^ (dh & 7)) * 8),
                    &Vs[db*128]);
        }
        __syncthreads();
        // QK^T + bias + exp -> Ps (swizzled), accumulate rowsum
        bf16x8 aq[2], kf8[8];
        #pragma unroll
        for (int i2 = 0; i2 < 2; ++i2)
            aq[i2] = *(const bf16x8*)&Qs[(wr0 + i2*16 + fr)*32 + fk];
        #pragma unroll
        for (int n2 = 0; n2 < 8; ++n2)
            kf8[n2] = *(const bf16x8*)&Ks[(n2*16 + fr)*32 + fk];
        #pragma unroll
        for (int i2 = 0; i2 < 2; ++i2) {
            #pragma unroll
            for (int n2 = 0; n2 < 8; ++n2) {
                f32x4 z = {0.f, 0.f, 0.f, 0.f};
                f32x4 s = __builtin_amdgcn_mfma_f32_16x16x32_bf16(aq[i2], kf8[n2], z, 0, 0, 0);
                const int jg = J0 + n2*16 + fr;
                #pragma unroll
                for (int r2 = 0; r2 < 4; ++r2) {
                    const int rloc = wr0 + i2*16 + fq4 + r2;
                    const float l = s[r2] + biasb[((size_t)b*N_ + I0 + rloc)*N_ + jg];
                    const float p = exp2f(fminf(l, 80.f) * LOG2E);
                    rsum[i2][r2] += p;
                    int idx = rloc*128 + n2*16 + fr;
                    idx ^= (rloc & 7) << 3;
                    Ps[idx] = bf16s(p);
                }
            }
        }
        __syncthreads();
        // PV accumulate: apv += P(128x128) @ V^T(32x128)
        #pragma unroll
        for (int ks = 0; ks < 4; ++ks) {
            bf16x8 ap[2], bv[2];
            #pragma unroll
            for (int i2 = 0; i2 < 2; ++i2) {
                const int r = wr0 + i2*16 + fr;
                int idx = r*128 + ks*32 + fk;
                idx ^= (r & 7) << 3;
                ap[i2] = *(const bf16x8*)&Ps[idx];
            }
            #pragma unroll
            for (int n2 = 0; n2 < 2; ++n2) {
                const int dh = n2*16 + fr;
                const int q = lane >> 4;
                const int slot = (ks*4 + q) ^ (dh & 7);
                bv[n2] = *(const bf16x8*)&Vs[dh*128 + slot*8];
            }
            #pragma unroll
            for (int i2 = 0; i2 < 2; ++i2)
                #pragma unroll
                for (int n2 = 0; n2 < 2; ++n2)
                    apv[i2][n2] = __builtin_amdgcn_mfma_f32_16x16x32_bf16(
                            ap[i2], bv[n2], apv[i2][n2], 0, 0, 0);
        }
    }
    // reduce rowsum across the 16-lane j-groups
    #pragma unroll
    for (int i2 = 0; i2 < 2; ++i2)
        #pragma unroll
        for (int r2 = 0; r2 < 4; ++r2)
            #pragma unroll
            for (int o = 1; o < 16; o <<= 1)
                rsum[i2][r2] += __shfl_xor(rsum[i2][r2], o);
    #pragma unroll
    for (int i2 = 0; i2 < 2; ++i2) {
        #pragma unroll
        for (int r2 = 0; r2 < 4; ++r2) {
            const int row = wr0 + i2*16 + fq4 + r2;
            if (fr == 0)
                rowsum[(size_t)bh*N_ + I0 + row] = rsum[i2][r2];
            const float inv = 1.f / rsum[i2][r2];
            #pragma unroll
            for (int n2 = 0; n2 < 2; ++n2)
                actx[((size_t)b*N_ + I0 + row)*D_ + h*HD_ + n2*16 + fr]
                    = bf16s(apv[i2][n2][r2] * inv);
        }
    }
}

// ---------------- LN helpers (wave per row of 256) ---------------------------
__device__ inline void ln_core(float v[4], int lane, const float* __restrict__ g,
        const float* __restrict__ bt, float out[4])
{
    float s  = v[0] + v[1] + v[2] + v[3];
    float sq = v[0]*v[0] + v[1]*v[1] + v[2]*v[2] + v[3]*v[3];
    for (int o = 1; o < 64; o <<= 1) { s += __shfl_xor(s, o); sq += __shfl_xor(sq, o); }
    float mean = s * (1.f/D_);
    float rstd = rsqrtf(sq * (1.f/D_) - mean*mean + 1e-5f);
    const float4 gv = *(const float4*)(g  + lane*4);
    const float4 bv = *(const float4*)(bt + lane*4);
    out[0] = (v[0]-mean)*rstd*gv.x + bv.x;
    out[1] = (v[1]-mean)*rstd*gv.y + bv.y;
    out[2] = (v[2]-mean)*rstd*gv.z + bv.z;
    out[3] = (v[3]-mean)*rstd*gv.w + bv.w;
}

// xn = LN(x^T + aout); writes f32 + bf16
__global__ __launch_bounds__(256) void ln_xn(const float* __restrict__ x,
        const float* __restrict__ aout, const float* __restrict__ g,
        const float* __restrict__ bt, float* __restrict__ xn, short* __restrict__ xnb)
{
    int row = blockIdx.x*4 + (threadIdx.x >> 6);
    int lane = threadIdx.x & 63;
    int b = row / N_, n = row % N_;
    const float4 xv = *(const float4*)(x + ((size_t)n*B_ + b)*D_ + lane*4);
    const float4 av = *(const float4*)(aout + (size_t)row*D_ + lane*4);
    float v[4] = {xv.x+av.x, xv.y+av.y, xv.z+av.z, xv.w+av.w};
    float o[4];
    ln_core(v, lane, g, bt, o);
    *(float4*)(xn + (size_t)row*D_ + lane*4) = make_float4(o[0], o[1], o[2], o[3]);
    short4 s4; s4.x = bf16s(o[0]); s4.y = bf16s(o[1]); s4.z = bf16s(o[2]); s4.w = bf16s(o[3]);
    *(short4*)(xnb + (size_t)row*D_ + lane*4) = s4;
}

// e2 = LN(e + w*gathered), w recomputed from q,k,bias,rowsum (no P buffer)
__global__ __launch_bounds__(256) void edge_update(const float* __restrict__ e,
        const float* __restrict__ x, const int* __restrict__ ei,
        const short* __restrict__ qkb, const float* __restrict__ biasb,
        const float* __restrict__ rowsum, const float* __restrict__ g,
        const float* __restrict__ bt, float* __restrict__ e2f, short* __restrict__ e2b)
{
    long row = (long)blockIdx.x*4 + (threadIdx.x >> 6);   // b*N*K + i*K + k
    int lane = threadIdx.x & 63;
    long bi = row >> 4;          // / K_
    long b = bi / N_; int i = (int)(bi % N_);
    int ej = ei[row];
    // --- recompute w = (1/H) sum_h exp(q_ej . k_i + bias) / rowsum[h,ej] ---
    const short4 q4 = *(const short4*)(qkb + ((size_t)b*N_ + ej)*512 + lane*4);
    const short4 k4 = *(const short4*)(qkb + ((size_t)b*N_ + i)*512 + 256 + lane*4);
    float dot = b2f(q4.x)*b2f(k4.x) + b2f(q4.y)*b2f(k4.y)
              + b2f(q4.z)*b2f(k4.z) + b2f(q4.w)*b2f(k4.w);
    dot += __shfl_xor(dot, 1); dot += __shfl_xor(dot, 2); dot += __shfl_xor(dot, 4);
    const int h = lane >> 3;
    const float l = dot + biasb[((size_t)b*N_ + ej)*N_ + i];
    float p = exp2f(fminf(l, 80.f) * 1.4426950408889634f)
            / rowsum[((size_t)b*H_ + h)*N_ + ej];
    p += __shfl_xor(p, 8); p += __shfl_xor(p, 16); p += __shfl_xor(p, 32);
    const float w = p * (1.f/H_);
    // --- e2 = LN(e + w * x[ej]) ---
    const float4 ev = *(const float4*)(e + row*D_ + lane*4);
    const float4 xv = *(const float4*)(x + ((size_t)ej*B_ + b)*D_ + lane*4);
    float v[4] = {ev.x + w*xv.x, ev.y + w*xv.y, ev.z + w*xv.z, ev.w + w*xv.w};
    float o[4];
    ln_core(v, lane, g, bt, o);
    *(float4*)(e2f + row*D_ + lane*4) = make_float4(o[0], o[1], o[2], o[3]);
    short4 s4; s4.x = bf16s(o[0]); s4.y = bf16s(o[1]); s4.z = bf16s(o[2]); s4.w = bf16s(o[3]);
    *(short4*)(e2b + row*D_ + lane*4) = s4;
}

// ============================================================================
extern "C" void kernel_launch(void* const* d_in, const int* in_sizes, int n_in,
                              void* d_out, int out_size, void* d_ws, size_t ws_size,
                              hipStream_t stream)
{
    (void)in_sizes; (void)n_in; (void)out_size; (void)ws_size;
    const float* x    = (const float*)d_in[0];
    const float* e    = (const float*)d_in[1];
    const int*   ei   = (const int*)d_in[2];
    const float* Wq   = (const float*)d_in[3];
    const float* bq   = (const float*)d_in[4];
    const float* Wk   = (const float*)d_in[5];
    const float* bk   = (const float*)d_in[6];
    const float* Wv   = (const float*)d_in[7];
    const float* bv   = (const float*)d_in[8];
    const float* Wo   = (const float*)d_in[9];
    const float* bo   = (const float*)d_in[10];
    const float* nW1  = (const float*)d_in[11];
    const float* nb1  = (const float*)d_in[12];
    const float* nW2  = (const float*)d_in[13];
    const float* nb2  = (const float*)d_in[14];
    const float* eW1  = (const float*)d_in[15];
    const float* eb1  = (const float*)d_in[16];
    const float* eW2  = (const float*)d_in[17];
    const float* eb2  = (const float*)d_in[18];
    const float* na_g = (const float*)d_in[19];
    const float* na_b = (const float*)d_in[20];
    const float* ea_g = (const float*)d_in[21];
    const float* ea_b = (const float*)d_in[22];
    const float* nf_g = (const float*)d_in[23];
    const float* nf_b = (const float*)d_in[24];
    const float* ef_g = (const float*)d_in[25];
    const float* ef_b = (const float*)d_in[26];

    float* out1 = (float*)d_out;                       // (N,B,D)
    float* e2f  = out1 + (size_t)N_*B_*D_;             // (B,N,K,D) — e2 intermediate + final

    char* wp = (char*)d_ws;
    auto alloc = [&](size_t bytes) -> char* {
        char* p = wp; wp += (bytes + 255) & ~(size_t)255; return p;
    };
    short* xtb    = (short*)alloc((size_t)M_*D_*2);
    short* WqkvT  = (short*)alloc((size_t)768*D_*2);
    float* bqkv   = (float*)alloc(768*4);
    short* WoT    = (short*)alloc((size_t)D_*D_*2);
    short* nW1T   = (short*)alloc((size_t)F_*D_*2);
    short* nW2T   = (short*)alloc((size_t)D_*F_*2);
    short* eW1T   = (short*)alloc((size_t)F_*D_*2);
    short* eW2T   = (short*)alloc((size_t)D_*F_*2);
    float* means  = (float*)alloc((size_t)R_*4);
    float* biasb  = (float*)alloc((size_t)B_*N_*N_*4);
    short* qkb    = (short*)alloc((size_t)M_*512*2);
    short* vtb    = (short*)alloc((size_t)B_*H_*HD_*N_*2);
    float* rowsum = (float*)alloc((size_t)B_*H_*N_*4);
    short* actx   = (short*)alloc((size_t)M_*D_*2);
    float* aout   = (float*)alloc((size_t)M_*D_*4);
    float* xn     = (float*)alloc((size_t)M_*D_*4);
    short* xnb    = (short*)alloc((size_t)M_*D_*2);
    short* nhid   = (short*)alloc((size_t)M_*F_*2);
    short* e2b    = (short*)alloc((size_t)R_*D_*2);
    short* ehid   = (short*)alloc((size_t)RC_*F_*2);

    // ---- weight prep ----
    transposeW<<<dim3(D_/32, D_/32), 256, 0, stream>>>(Wq, WqkvT,           D_, D_, 0.17677669529663687f);
    transposeW<<<dim3(D_/32, D_/32), 256, 0, stream>>>(Wk, WqkvT + 256*D_,  D_, D_, 1.f);
    transposeW<<<dim3(D_/32, D_/32), 256, 0, stream>>>(Wv, WqkvT + 512*D_,  D_, D_, 1.f);
    build_bqkv<<<3, 256, 0, stream>>>(bq, bk, bv, bqkv);
    transposeW<<<dim3(D_/32, D_/32), 256, 0, stream>>>(Wo, WoT, D_, D_, 1.f);
    transposeW<<<dim3(F_/32, D_/32), 256, 0, stream>>>(nW1, nW1T, D_, F_, 1.f);
    transposeW<<<dim3(D_/32, F_/32), 256, 0, stream>>>(nW2, nW2T, F_, D_, 1.f);
    transposeW<<<dim3(F_/32, D_/32), 256, 0, stream>>>(eW1, eW1T, D_, F_, 1.f);
    transposeW<<<dim3(D_/32, F_/32), 256, 0, stream>>>(eW2, eW2T, F_, D_, 1.f);
    conv_x<<<M_, 256, 0, stream>>>(x, xtb);

    // ---- attn bias ----
    edge_means<<<R_/4, 256, 0, stream>>>(e, means);
    zero4<<<2048, 256, 0, stream>>>((float4*)biasb, (long)B_*N_*N_/4);
    scatter_bias<<<(M_ + 255)/256, 256, 0, stream>>>(ei, means, biasb);

    // ---- QKV (fused, q-scale folded into Wq/bq) ----
    gemm_bf16<false,2><<<dim3(M_/128, 768/128), 256, 0, stream>>>(
            xtb, WqkvT, bqkv, nullptr, qkb, vtb, 768, D_);

    // ---- attention (fused flash-style) ----
    attn_fused<<<dim3(N_/128, B_*H_), 256, 0, stream>>>(qkb, vtb, biasb, rowsum, actx);
    gemm_bf16<false,0><<<dim3(M_/128, D_/128), 256, 0, stream>>>(
            actx, WoT, bo, aout, nullptr, nullptr, D_, D_);

    // ---- node path ----
    ln_xn<<<M_/4, 256, 0, stream>>>(x, aout, na_g, na_b, xn, xnb);
    gemm_bf16<true,1><<<dim3(M_/128, F_/128), 256, 0, stream>>>(
            xnb, nW1T, nb1, nullptr, nhid, nullptr, F_, D_);
    gemm_ln<true><<<M_/64, 256, 0, stream>>>(
            nhid, nW2T, nb2, xn, nf_g, nf_b, out1, F_);

    // ---- edge path (w recomputed inline; no P / wmean buffers) ----
    edge_update<<<R_/4, 256, 0, stream>>>(e, x, ei, qkb, biasb, rowsum,
            ea_g, ea_b, e2f, e2b);
    for (int c = 0; c < NCH_; ++c) {
        gemm_bf16<true,1><<<dim3(RC_/128, F_/128), 256, 0, stream>>>(
                e2b + (size_t)c*RC_*D_, eW1T, eb1, nullptr, ehid, nullptr, F_, D_);
        gemm_ln<false><<<RC_/64, 256, 0, stream>>>(
                ehid, eW2T, eb2, e2f + (size_t)c*RC_*D_, ef_g, ef_b,
                e2f + (size_t)c*RC_*D_, F_);
    }
}

// Round 4
// 367.040 us; speedup vs baseline: 1.8909x; 1.1670x over previous
//
#include <hip/hip_runtime.h>
#include <hip/hip_bf16.h>
#include <math.h>

#define B_ 8
#define N_ 512
#define K_ 16
#define D_ 256
#define F_ 1024
#define H_ 8
#define HD_ 32
#define M_ (B_*N_)      // 4096 rows (b,n)
#define R_ (B_*N_*K_)   // 65536 edge rows

typedef __bf16 bf16x8 __attribute__((ext_vector_type(8)));
typedef float  f32x4  __attribute__((ext_vector_type(4)));

__device__ inline short bf16s(float f) {
    __hip_bfloat16 h = __float2bfloat16(f);
    return *reinterpret_cast<short*>(&h);
}
__device__ inline float b2f(short s) {
    union { float f; unsigned u; } v; v.u = ((unsigned)(unsigned short)s) << 16; return v.f;
}

// async global->LDS, 16B per lane; lds base must be wave-uniform (dest = base + lane*16)
__device__ __forceinline__ void gload16(const short* g, short* l) {
    __builtin_amdgcn_global_load_lds(
        (const __attribute__((address_space(1))) unsigned int*)g,
        (__attribute__((address_space(3))) unsigned int*)l, 16, 0, 0);
}

// ---------------- all weight transposes in one launch (grid.z selects) ------
__global__ __launch_bounds__(256) void transposeAll(
        const float* __restrict__ Wq, const float* __restrict__ Wk,
        const float* __restrict__ Wv, const float* __restrict__ Wo,
        const float* __restrict__ nW1, const float* __restrict__ nW2,
        const float* __restrict__ eW1, const float* __restrict__ eW2,
        short* __restrict__ WqkvT, short* __restrict__ WoT,
        short* __restrict__ nW1T, short* __restrict__ nW2T,
        short* __restrict__ eW1T, short* __restrict__ eW2T)
{
    const float* W; short* WT; int Kk, Nn; float sc = 1.f;
    switch (blockIdx.z) {
        case 0: W=Wq;  WT=WqkvT;          Kk=256;  Nn=256;  sc=0.17677669529663687f; break;
        case 1: W=Wk;  WT=WqkvT+256*256;  Kk=256;  Nn=256;  break;
        case 2: W=Wv;  WT=WqkvT+512*256;  Kk=256;  Nn=256;  break;
        case 3: W=Wo;  WT=WoT;            Kk=256;  Nn=256;  break;
        case 4: W=nW1; WT=nW1T;           Kk=256;  Nn=1024; break;
        case 5: W=nW2; WT=nW2T;           Kk=1024; Nn=256;  break;
        case 6: W=eW1; WT=eW1T;           Kk=256;  Nn=1024; break;
        default:W=eW2; WT=eW2T;           Kk=1024; Nn=256;  break;
    }
    const int bx = blockIdx.x, by = blockIdx.y;
    if (bx >= Nn/32 || by >= Kk/32) return;
    __shared__ float tile[32][33];
    int tx = threadIdx.x & 31, ty = threadIdx.x >> 5;   // 32x8
    #pragma unroll
    for (int j = 0; j < 4; ++j) {
        int k = by*32 + ty + j*8;
        tile[ty + j*8][tx] = W[(size_t)k*Nn + bx*32 + tx];
    }
    __syncthreads();
    #pragma unroll
    for (int j = 0; j < 4; ++j) {
        int n = bx*32 + ty + j*8;
        WT[(size_t)n*Kk + by*32 + tx] = bf16s(tile[tx][ty + j*8] * sc);
    }
}

__global__ __launch_bounds__(256) void build_bqkv(const float* __restrict__ bq,
        const float* __restrict__ bk, const float* __restrict__ bv,
        float* __restrict__ bqkv)
{
    int t = blockIdx.x*256 + threadIdx.x;
    if (t >= 768) return;
    float v = (t < 256) ? bq[t]*0.17677669529663687f
            : (t < 512) ? bk[t-256] : bv[t-512];
    bqkv[t] = v;
}

// ---------------- x (N,B,D) f32 -> xtb (B*N, D) bf16 ------------------------
__global__ __launch_bounds__(256) void conv_x(const float* __restrict__ x,
        short* __restrict__ xtb)
{
    int row = blockIdx.x;         // b*N+n
    int d = threadIdx.x;
    int b = row >> 9, n = row & 511;
    xtb[(size_t)row*D_ + d] = bf16s(x[((size_t)n*B_ + b)*D_ + d]);
}

// ---------------- means[b,i,k] = mean_d e ----------------------------------
__global__ __launch_bounds__(256) void edge_means(const float* __restrict__ e,
        float* __restrict__ means)
{
    long row = (long)blockIdx.x*4 + (threadIdx.x >> 6);
    int lane = threadIdx.x & 63;
    float4 v = ((const float4*)(e + row*D_))[lane];
    float s = v.x + v.y + v.z + v.w;
    for (int o = 1; o < 64; o <<= 1) s += __shfl_xor(s, o);
    if (lane == 0) means[row] = s * (1.f/D_);
}

// zero 16 rows + serial per-row scatter (numpy last-wins) in one kernel
__global__ __launch_bounds__(256) void bias_build(const int* __restrict__ ei,
        const float* __restrict__ means, float* __restrict__ biasb)
{
    const int r0 = blockIdx.x * 16;       // 16 (b,i) rows per block
    float4* bp4 = (float4*)(biasb + (size_t)r0*N_);
    #pragma unroll
    for (int i = threadIdx.x; i < 16*N_/4; i += 256)
        bp4[i] = make_float4(0.f, 0.f, 0.f, 0.f);
    __syncthreads();
    if (threadIdx.x < 16) {
        const int idx = r0 + threadIdx.x;
        const int* ep = ei + (size_t)idx*K_;
        const float* mp = means + (size_t)idx*K_;
        float* bp = biasb + (size_t)idx*N_;
        for (int k = 0; k < K_; ++k) bp[ep[k]] = mp[k];
    }
}

// ---------------- generic bf16 MFMA GEMM: C = A[M,K] @ BT[N,K]^T + bias -----
// OUTMODE: 0 = f32 Cf, 1 = bf16 Cb, 2 = qkv split (cols<512 -> Cb[.,512], cols>=512 -> vtb transposed)
template<bool GELU, int OUTMODE>
__global__ __launch_bounds__(256) void gemm_bf16(
        const short* __restrict__ A, const short* __restrict__ BT,
        const float* __restrict__ bias, float* __restrict__ Cf,
        short* __restrict__ Cb, short* __restrict__ vtb, int Nn, int Kk)
{
    __shared__ __align__(16) short As[128*32];
    __shared__ __align__(16) short Bs[128*32];
    const int t = threadIdx.x;
    const int lane = t & 63;
    const int wave = t >> 6;
    const int wr = (wave >> 1) * 64;
    const int wc = (wave & 1) * 64;
    const int bm = blockIdx.x, bn = blockIdx.y;
    f32x4 acc[4][4] = {};
    const int srow = lane >> 2;       // staging row within 16-row group
    const int sk   = (lane & 3) * 8;  // staging k offset (8 bf16 = 16B)
    const int fr = lane & 15;
    const int fk = (lane >> 4) * 8;
    for (int k0 = 0; k0 < Kk; k0 += 32) {
        __syncthreads();
        #pragma unroll
        for (int i = 0; i < 2; ++i) {
            const int rb = wave*16 + i*64;
            gload16(A  + (size_t)(bm*128 + rb + srow)*Kk + k0 + sk, &As[rb*32]);
            gload16(BT + (size_t)(bn*128 + rb + srow)*Kk + k0 + sk, &Bs[rb*32]);
        }
        __syncthreads();
        bf16x8 af[4], bfr[4];
        #pragma unroll
        for (int i2 = 0; i2 < 4; ++i2)
            af[i2] = *(const bf16x8*)&As[(wr + i2*16 + fr)*32 + fk];
        #pragma unroll
        for (int n2 = 0; n2 < 4; ++n2)
            bfr[n2] = *(const bf16x8*)&Bs[(wc + n2*16 + fr)*32 + fk];
        #pragma unroll
        for (int i2 = 0; i2 < 4; ++i2)
            #pragma unroll
            for (int n2 = 0; n2 < 4; ++n2)
                acc[i2][n2] = __builtin_amdgcn_mfma_f32_16x16x32_bf16(
                        af[i2], bfr[n2], acc[i2][n2], 0, 0, 0);
    }
    const int fq4 = (lane >> 4) * 4;
    #pragma unroll
    for (int i2 = 0; i2 < 4; ++i2) {
        #pragma unroll
        for (int n2 = 0; n2 < 4; ++n2) {
            const int col = bn*128 + wc + n2*16 + fr;
            const float bv = bias[col];
            if constexpr (OUTMODE == 2) {
                const int rowb = bm*128 + wr + i2*16 + fq4;
                if (col < 512) {
                    #pragma unroll
                    for (int r2 = 0; r2 < 4; ++r2)
                        Cb[(size_t)(rowb + r2)*512 + col] = bf16s(acc[i2][n2][r2] + bv);
                } else {
                    const int b = rowb >> 9, n = rowb & 511;
                    const int dv = col - 512, h = dv >> 5, dh = dv & 31;
                    short4 s4;
                    s4.x = bf16s(acc[i2][n2][0] + bv);
                    s4.y = bf16s(acc[i2][n2][1] + bv);
                    s4.z = bf16s(acc[i2][n2][2] + bv);
                    s4.w = bf16s(acc[i2][n2][3] + bv);
                    *(short4*)&vtb[((size_t)((b*H_ + h)*HD_ + dh))*512 + n] = s4;
                }
            } else {
                #pragma unroll
                for (int r2 = 0; r2 < 4; ++r2) {
                    const int row = bm*128 + wr + i2*16 + fq4 + r2;
                    float v = acc[i2][n2][r2] + bv;
                    if constexpr (GELU) v = 0.5f*v*(1.f + erff(v*0.70710678118654752f));
                    if constexpr (OUTMODE == 0) Cf[(size_t)row*Nn + col] = v;
                    if constexpr (OUTMODE == 1) Cb[(size_t)row*Nn + col] = bf16s(v);
                }
            }
        }
    }
}

// ---------------- GEMM + bias + residual + LayerNorm, 64x256 tile ----------
// RESBF: residual read from bf16 buffer (edge path) instead of f32
template<bool TRANSOUT, bool RESBF>
__global__ __launch_bounds__(256) void gemm_ln(
        const short* __restrict__ A, const short* __restrict__ BT,
        const float* __restrict__ bias, const float* __restrict__ resf,
        const short* __restrict__ resb,
        const float* __restrict__ g, const float* __restrict__ bt,
        float* __restrict__ out, int Kk)
{
    __shared__ __align__(16) short As[64*32];
    __shared__ __align__(16) short Bs[256*32];
    __shared__ float rs[64][4][2];
    __shared__ float mr[64][2];
    const int t = threadIdx.x;
    const int lane = t & 63;
    const int wave = t >> 6;
    const int wc = wave * 64;
    const int bm = blockIdx.x;
    f32x4 acc[4][4] = {};
    const int srow = lane >> 2;
    const int sk   = (lane & 3) * 8;
    const int fr = lane & 15;
    const int fk = (lane >> 4) * 8;
    for (int k0 = 0; k0 < Kk; k0 += 32) {
        __syncthreads();
        {
            const int rb = wave*16;
            gload16(A + (size_t)(bm*64 + rb + srow)*Kk + k0 + sk, &As[rb*32]);
        }
        #pragma unroll
        for (int i = 0; i < 4; ++i) {
            const int rb = wave*16 + i*64;
            gload16(BT + (size_t)(rb + srow)*Kk + k0 + sk, &Bs[rb*32]);
        }
        __syncthreads();
        bf16x8 af[4], bfr[4];
        #pragma unroll
        for (int i2 = 0; i2 < 4; ++i2)
            af[i2] = *(const bf16x8*)&As[(i2*16 + fr)*32 + fk];
        #pragma unroll
        for (int n2 = 0; n2 < 4; ++n2)
            bfr[n2] = *(const bf16x8*)&Bs[(wc + n2*16 + fr)*32 + fk];
        #pragma unroll
        for (int i2 = 0; i2 < 4; ++i2)
            #pragma unroll
            for (int n2 = 0; n2 < 4; ++n2)
                acc[i2][n2] = __builtin_amdgcn_mfma_f32_16x16x32_bf16(
                        af[i2], bfr[n2], acc[i2][n2], 0, 0, 0);
    }
    const int fq4 = (lane >> 4) * 4;
    float ps[4][4] = {}, pq[4][4] = {};
    #pragma unroll
    for (int i2 = 0; i2 < 4; ++i2) {
        #pragma unroll
        for (int n2 = 0; n2 < 4; ++n2) {
            const int c = wc + n2*16 + fr;
            const float bv = bias[c];
            #pragma unroll
            for (int r2 = 0; r2 < 4; ++r2) {
                const int row = i2*16 + fq4 + r2;
                const size_t grow = (size_t)bm*64 + row;
                float rv;
                if constexpr (RESBF) rv = b2f(resb[grow*256 + c]);
                else                 rv = resf[grow*256 + c];
                float v = acc[i2][n2][r2] + bv + rv;
                acc[i2][n2][r2] = v;
                ps[i2][r2] += v;
                pq[i2][r2] += v*v;
            }
        }
    }
    #pragma unroll
    for (int i2 = 0; i2 < 4; ++i2)
        #pragma unroll
        for (int r2 = 0; r2 < 4; ++r2)
            #pragma unroll
            for (int o = 1; o < 16; o <<= 1) {
                ps[i2][r2] += __shfl_xor(ps[i2][r2], o);
                pq[i2][r2] += __shfl_xor(pq[i2][r2], o);
            }
    if ((lane & 15) == 0) {
        #pragma unroll
        for (int i2 = 0; i2 < 4; ++i2)
            #pragma unroll
            for (int r2 = 0; r2 < 4; ++r2) {
                const int row = i2*16 + fq4 + r2;
                rs[row][wave][0] = ps[i2][r2];
                rs[row][wave][1] = pq[i2][r2];
            }
    }
    __syncthreads();
    if (t < 64) {
        float S = 0.f, Q = 0.f;
        #pragma unroll
        for (int w = 0; w < 4; ++w) { S += rs[t][w][0]; Q += rs[t][w][1]; }
        const float mean = S * (1.f/D_);
        mr[t][0] = mean;
        mr[t][1] = rsqrtf(Q * (1.f/D_) - mean*mean + 1e-5f);
    }
    __syncthreads();
    #pragma unroll
    for (int i2 = 0; i2 < 4; ++i2) {
        #pragma unroll
        for (int n2 = 0; n2 < 4; ++n2) {
            const int c = wc + n2*16 + fr;
            const float gv = g[c], bv2 = bt[c];
            #pragma unroll
            for (int r2 = 0; r2 < 4; ++r2) {
                const int row = i2*16 + fq4 + r2;
                const size_t grow = (size_t)bm*64 + row;
                const float o = (acc[i2][n2][r2] - mr[row][0])*mr[row][1]*gv + bv2;
                if constexpr (TRANSOUT) {
                    const int bb = (int)(grow >> 9), nn = (int)(grow & 511);
                    out[((size_t)nn*B_ + bb)*D_ + c] = o;
                } else {
                    out[grow*256 + c] = o;
                }
            }
        }
    }
}

// ---------------- fused flash attention: QK^T+bias -> exp -> PV -------------
__global__ __launch_bounds__(256) void attn_fused(const short* __restrict__ qkb,
        const short* __restrict__ vtb, const float* __restrict__ biasb,
        float* __restrict__ rowsum, short* __restrict__ actx)
{
    __shared__ __align__(16) short Qs[128*32];
    __shared__ __align__(16) short Ks[128*32];
    __shared__ __align__(16) short Vs[32*128];     // [dh][j], source-pre-swizzled
    __shared__ __align__(16) short Ps[128*128];    // XOR-swizzled bf16 P tile
    const int it = blockIdx.x, bh = blockIdx.y;
    const int b = bh >> 3, h = bh & 7;
    const int t = threadIdx.x;
    const int lane = t & 63;
    const int wave = t >> 6;
    const int wr0 = wave * 32;
    const int srow = lane >> 2;        // staging: 16 rows x 64B
    const int sk   = (lane & 3) * 8;
    const int srow8 = lane >> 4;       // staging: 4 rows x 256B
    const int ck16  = lane & 15;       // 16B chunk index within 128-col row
    const int fr = lane & 15;
    const int fk = (lane >> 4) * 8;
    const int fq4 = (lane >> 4) * 4;
    const int I0 = it * 128;
    #pragma unroll
    for (int i = 0; i < 2; ++i) {
        const int rb = wave*16 + i*64;
        gload16(qkb + (size_t)(b*N_ + I0 + rb + srow)*512 + h*HD_ + sk, &Qs[rb*32]);
    }
    float rsum[2][4] = {};
    f32x4 apv[2][2] = {};
    const float LOG2E = 1.4426950408889634f;
    for (int jt = 0; jt < 4; ++jt) {
        const int J0 = jt * 128;
        __syncthreads();
        #pragma unroll
        for (int i = 0; i < 2; ++i) {
            const int rb = wave*16 + i*64;
            gload16(qkb + (size_t)(b*N_ + J0 + rb + srow)*512 + 256 + h*HD_ + sk, &Ks[rb*32]);
        }
        #pragma unroll
        for (int i = 0; i < 2; ++i) {
            const int db = wave*8 + i*4;
            const int dh = db + srow8;
            gload16(vtb + ((size_t)bh*HD_ + dh)*512 + J0 + ((ck16 ^ (dh & 7)) * 8),
                    &Vs[db*128]);
        }
        __syncthreads();
        bf16x8 aq[2], kf8[8];
        #pragma unroll
        for (int i2 = 0; i2 < 2; ++i2)
            aq[i2] = *(const bf16x8*)&Qs[(wr0 + i2*16 + fr)*32 + fk];
        #pragma unroll
        for (int n2 = 0; n2 < 8; ++n2)
            kf8[n2] = *(const bf16x8*)&Ks[(n2*16 + fr)*32 + fk];
        #pragma unroll
        for (int i2 = 0; i2 < 2; ++i2) {
            #pragma unroll
            for (int n2 = 0; n2 < 8; ++n2) {
                f32x4 z = {0.f, 0.f, 0.f, 0.f};
                f32x4 s = __builtin_amdgcn_mfma_f32_16x16x32_bf16(aq[i2], kf8[n2], z, 0, 0, 0);
                const int jg = J0 + n2*16 + fr;
                #pragma unroll
                for (int r2 = 0; r2 < 4; ++r2) {
                    const int rloc = wr0 + i2*16 + fq4 + r2;
                    const float l = s[r2] + biasb[((size_t)b*N_ + I0 + rloc)*N_ + jg];
                    const float p = exp2f(fminf(l, 80.f) * LOG2E);
                    rsum[i2][r2] += p;
                    int idx = rloc*128 + n2*16 + fr;
                    idx ^= (rloc & 7) << 3;
                    Ps[idx] = bf16s(p);
                }
            }
        }
        __syncthreads();
        #pragma unroll
        for (int ks = 0; ks < 4; ++ks) {
            bf16x8 ap[2], bv[2];
            #pragma unroll
            for (int i2 = 0; i2 < 2; ++i2) {
                const int r = wr0 + i2*16 + fr;
                int idx = r*128 + ks*32 + fk;
                idx ^= (r & 7) << 3;
                ap[i2] = *(const bf16x8*)&Ps[idx];
            }
            #pragma unroll
            for (int n2 = 0; n2 < 2; ++n2) {
                const int dh = n2*16 + fr;
                const int q = lane >> 4;
                const int slot = (ks*4 + q) ^ (dh & 7);
                bv[n2] = *(const bf16x8*)&Vs[dh*128 + slot*8];
            }
            #pragma unroll
            for (int i2 = 0; i2 < 2; ++i2)
                #pragma unroll
                for (int n2 = 0; n2 < 2; ++n2)
                    apv[i2][n2] = __builtin_amdgcn_mfma_f32_16x16x32_bf16(
                            ap[i2], bv[n2], apv[i2][n2], 0, 0, 0);
        }
    }
    #pragma unroll
    for (int i2 = 0; i2 < 2; ++i2)
        #pragma unroll
        for (int r2 = 0; r2 < 4; ++r2)
            #pragma unroll
            for (int o = 1; o < 16; o <<= 1)
                rsum[i2][r2] += __shfl_xor(rsum[i2][r2], o);
    #pragma unroll
    for (int i2 = 0; i2 < 2; ++i2) {
        #pragma unroll
        for (int r2 = 0; r2 < 4; ++r2) {
            const int row = wr0 + i2*16 + fq4 + r2;
            if (fr == 0)
                rowsum[(size_t)bh*N_ + I0 + row] = rsum[i2][r2];
            const float inv = 1.f / rsum[i2][r2];
            #pragma unroll
            for (int n2 = 0; n2 < 2; ++n2)
                actx[((size_t)b*N_ + I0 + row)*D_ + h*HD_ + n2*16 + fr]
                    = bf16s(apv[i2][n2][r2] * inv);
        }
    }
}

// ---------------- LN helpers (wave per row of 256) ---------------------------
__device__ inline void ln_core(float v[4], int lane, const float* __restrict__ g,
        const float* __restrict__ bt, float out[4])
{
    float s  = v[0] + v[1] + v[2] + v[3];
    float sq = v[0]*v[0] + v[1]*v[1] + v[2]*v[2] + v[3]*v[3];
    for (int o = 1; o < 64; o <<= 1) { s += __shfl_xor(s, o); sq += __shfl_xor(sq, o); }
    float mean = s * (1.f/D_);
    float rstd = rsqrtf(sq * (1.f/D_) - mean*mean + 1e-5f);
    const float4 gv = *(const float4*)(g  + lane*4);
    const float4 bv = *(const float4*)(bt + lane*4);
    out[0] = (v[0]-mean)*rstd*gv.x + bv.x;
    out[1] = (v[1]-mean)*rstd*gv.y + bv.y;
    out[2] = (v[2]-mean)*rstd*gv.z + bv.z;
    out[3] = (v[3]-mean)*rstd*gv.w + bv.w;
}

// xn = LN(x^T + aout); writes f32 + bf16
__global__ __launch_bounds__(256) void ln_xn(const float* __restrict__ x,
        const float* __restrict__ aout, const float* __restrict__ g,
        const float* __restrict__ bt, float* __restrict__ xn, short* __restrict__ xnb)
{
    int row = blockIdx.x*4 + (threadIdx.x >> 6);
    int lane = threadIdx.x & 63;
    int b = row >> 9, n = row & 511;
    const float4 xv = *(const float4*)(x + ((size_t)n*B_ + b)*D_ + lane*4);
    const float4 av = *(const float4*)(aout + (size_t)row*D_ + lane*4);
    float v[4] = {xv.x+av.x, xv.y+av.y, xv.z+av.z, xv.w+av.w};
    float o[4];
    ln_core(v, lane, g, bt, o);
    *(float4*)(xn + (size_t)row*D_ + lane*4) = make_float4(o[0], o[1], o[2], o[3]);
    short4 s4; s4.x = bf16s(o[0]); s4.y = bf16s(o[1]); s4.z = bf16s(o[2]); s4.w = bf16s(o[3]);
    *(short4*)(xnb + (size_t)row*D_ + lane*4) = s4;
}

// e2 = LN(e + w*gathered), w recomputed from q,k,bias,rowsum; writes bf16 only
__global__ __launch_bounds__(256) void edge_update(const float* __restrict__ e,
        const float* __restrict__ x, const int* __restrict__ ei,
        const short* __restrict__ qkb, const float* __restrict__ biasb,
        const float* __restrict__ rowsum, const float* __restrict__ g,
        const float* __restrict__ bt, short* __restrict__ e2b)
{
    long row = (long)blockIdx.x*4 + (threadIdx.x >> 6);   // b*N*K + i*K + k
    int lane = threadIdx.x & 63;
    long bi = row >> 4;          // / K_
    long b = bi / N_; int i = (int)(bi % N_);
    int ej = ei[row];
    const short4 q4 = *(const short4*)(qkb + ((size_t)b*N_ + ej)*512 + lane*4);
    const short4 k4 = *(const short4*)(qkb + ((size_t)b*N_ + i)*512 + 256 + lane*4);
    float dot = b2f(q4.x)*b2f(k4.x) + b2f(q4.y)*b2f(k4.y)
              + b2f(q4.z)*b2f(k4.z) + b2f(q4.w)*b2f(k4.w);
    dot += __shfl_xor(dot, 1); dot += __shfl_xor(dot, 2); dot += __shfl_xor(dot, 4);
    const int h = lane >> 3;
    const float l = dot + biasb[((size_t)b*N_ + ej)*N_ + i];
    float p = exp2f(fminf(l, 80.f) * 1.4426950408889634f)
            / rowsum[((size_t)b*H_ + h)*N_ + ej];
    p += __shfl_xor(p, 8); p += __shfl_xor(p, 16); p += __shfl_xor(p, 32);
    const float w = p * (1.f/H_);
    const float4 ev = *(const float4*)(e + row*D_ + lane*4);
    const float4 xv = *(const float4*)(x + ((size_t)ej*B_ + b)*D_ + lane*4);
    float v[4] = {ev.x + w*xv.x, ev.y + w*xv.y, ev.z + w*xv.z, ev.w + w*xv.w};
    float o[4];
    ln_core(v, lane, g, bt, o);
    short4 s4; s4.x = bf16s(o[0]); s4.y = bf16s(o[1]); s4.z = bf16s(o[2]); s4.w = bf16s(o[3]);
    *(short4*)(e2b + row*D_ + lane*4) = s4;
}

// ============================================================================
extern "C" void kernel_launch(void* const* d_in, const int* in_sizes, int n_in,
                              void* d_out, int out_size, void* d_ws, size_t ws_size,
                              hipStream_t stream)
{
    (void)in_sizes; (void)n_in; (void)out_size; (void)ws_size;
    const float* x    = (const float*)d_in[0];
    const float* e    = (const float*)d_in[1];
    const int*   ei   = (const int*)d_in[2];
    const float* Wq   = (const float*)d_in[3];
    const float* bq   = (const float*)d_in[4];
    const float* Wk   = (const float*)d_in[5];
    const float* bk   = (const float*)d_in[6];
    const float* Wv   = (const float*)d_in[7];
    const float* bv   = (const float*)d_in[8];
    const float* Wo   = (const float*)d_in[9];
    const float* bo   = (const float*)d_in[10];
    const float* nW1  = (const float*)d_in[11];
    const float* nb1  = (const float*)d_in[12];
    const float* nW2  = (const float*)d_in[13];
    const float* nb2  = (const float*)d_in[14];
    const float* eW1  = (const float*)d_in[15];
    const float* eb1  = (const float*)d_in[16];
    const float* eW2  = (const float*)d_in[17];
    const float* eb2  = (const float*)d_in[18];
    const float* na_g = (const float*)d_in[19];
    const float* na_b = (const float*)d_in[20];
    const float* ea_g = (const float*)d_in[21];
    const float* ea_b = (const float*)d_in[22];
    const float* nf_g = (const float*)d_in[23];
    const float* nf_b = (const float*)d_in[24];
    const float* ef_g = (const float*)d_in[25];
    const float* ef_b = (const float*)d_in[26];

    float* out1 = (float*)d_out;                       // (N,B,D)
    float* e2f  = out1 + (size_t)N_*B_*D_;             // (B,N,K,D) final

    // ---- workspace: fixed region + overlay (pre-MLP buffers alias ehid) ----
    char* wp = (char*)d_ws;
    auto alloc = [&](size_t bytes) -> char* {
        char* p = wp; wp += (bytes + 255) & ~(size_t)255; return p;
    };
    // fixed (live across phases)
    short* WqkvT  = (short*)alloc((size_t)768*D_*2);
    float* bqkv   = (float*)alloc(768*4);
    short* WoT    = (short*)alloc((size_t)D_*D_*2);
    short* nW1T   = (short*)alloc((size_t)F_*D_*2);
    short* nW2T   = (short*)alloc((size_t)D_*F_*2);
    short* eW1T   = (short*)alloc((size_t)F_*D_*2);
    short* eW2T   = (short*)alloc((size_t)D_*F_*2);
    float* rowsum = (float*)alloc((size_t)B_*H_*N_*4);
    short* e2b    = (short*)alloc((size_t)R_*D_*2);
    // overlay: phase-A buffers (dead before edge MLP) alias ehid
    char* ov = wp;
    auto allocA = [&](size_t bytes) -> char* {
        char* p = ov; ov += (bytes + 255) & ~(size_t)255; return p;
    };
    short* xtb    = (short*)allocA((size_t)M_*D_*2);
    float* means  = (float*)allocA((size_t)R_*4);
    float* biasb  = (float*)allocA((size_t)B_*N_*N_*4);
    short* qkb    = (short*)allocA((size_t)M_*512*2);
    short* vtb    = (short*)allocA((size_t)B_*H_*HD_*N_*2);
    short* actx   = (short*)allocA((size_t)M_*D_*2);
    float* aout   = (float*)allocA((size_t)M_*D_*4);
    float* xn     = (float*)allocA((size_t)M_*D_*4);
    short* xnb    = (short*)allocA((size_t)M_*D_*2);
    short* nhid   = (short*)allocA((size_t)M_*F_*2);
    short* ehid   = (short*)wp;   // (R_, F_) bf16 = 134 MB, aliases all of phase-A

    // ---- weight prep (1 launch) + bias vector ----
    transposeAll<<<dim3(32, 32, 8), 256, 0, stream>>>(Wq, Wk, Wv, Wo,
            nW1, nW2, eW1, eW2, WqkvT, WoT, nW1T, nW2T, eW1T, eW2T);
    build_bqkv<<<3, 256, 0, stream>>>(bq, bk, bv, bqkv);
    conv_x<<<M_, 256, 0, stream>>>(x, xtb);

    // ---- attn bias ----
    edge_means<<<R_/4, 256, 0, stream>>>(e, means);
    bias_build<<<M_/16, 256, 0, stream>>>(ei, means, biasb);

    // ---- QKV (fused, q-scale folded into Wq/bq) ----
    gemm_bf16<false,2><<<dim3(M_/128, 768/128), 256, 0, stream>>>(
            xtb, WqkvT, bqkv, nullptr, qkb, vtb, 768, D_);

    // ---- attention (fused flash-style) ----
    attn_fused<<<dim3(N_/128, B_*H_), 256, 0, stream>>>(qkb, vtb, biasb, rowsum, actx);
    gemm_bf16<false,0><<<dim3(M_/128, D_/128), 256, 0, stream>>>(
            actx, WoT, bo, aout, nullptr, nullptr, D_, D_);

    // ---- node path ----
    ln_xn<<<M_/4, 256, 0, stream>>>(x, aout, na_g, na_b, xn, xnb);
    gemm_bf16<true,1><<<dim3(M_/128, F_/128), 256, 0, stream>>>(
            xnb, nW1T, nb1, nullptr, nhid, nullptr, F_, D_);
    gemm_ln<true,false><<<M_/64, 256, 0, stream>>>(
            nhid, nW2T, nb2, xn, nullptr, nf_g, nf_b, out1, F_);

    // ---- edge path (single full-size pass; ehid overlays dead buffers) ----
    edge_update<<<R_/4, 256, 0, stream>>>(e, x, ei, qkb, biasb, rowsum,
            ea_g, ea_b, e2b);
    gemm_bf16<true,1><<<dim3(R_/128, F_/128), 256, 0, stream>>>(
            e2b, eW1T, eb1, nullptr, ehid, nullptr, F_, D_);
    gemm_ln<false,true><<<R_/64, 256, 0, stream>>>(
            ehid, eW2T, eb2, nullptr, e2b, ef_g, ef_b, e2f, F_);
}

// Round 5
// 331.802 us; speedup vs baseline: 2.0918x; 1.1062x over previous
//
#include <hip/hip_runtime.h>
#include <hip/hip_bf16.h>
#include <math.h>

#define B_ 8
#define N_ 512
#define K_ 16
#define D_ 256
#define F_ 1024
#define H_ 8
#define HD_ 32
#define M_ (B_*N_)      // 4096 rows (b,n)
#define R_ (B_*N_*K_)   // 65536 edge rows

typedef __bf16 bf16x8 __attribute__((ext_vector_type(8)));
typedef float  f32x4  __attribute__((ext_vector_type(4)));

__device__ inline short bf16s(float f) {
    __hip_bfloat16 h = __float2bfloat16(f);
    return *reinterpret_cast<short*>(&h);
}
__device__ inline float b2f(short s) {
    union { float f; unsigned u; } v; v.u = ((unsigned)(unsigned short)s) << 16; return v.f;
}

// async global->LDS, 16B per lane; lds base must be wave-uniform (dest = base + lane*16)
__device__ __forceinline__ void gload16(const short* g, short* l) {
    __builtin_amdgcn_global_load_lds(
        (const __attribute__((address_space(1))) unsigned int*)g,
        (__attribute__((address_space(3))) unsigned int*)l, 16, 0, 0);
}

// ---------------- all weight transposes in one launch (grid.z selects) ------
__global__ __launch_bounds__(256) void transposeAll(
        const float* __restrict__ Wq, const float* __restrict__ Wk,
        const float* __restrict__ Wv, const float* __restrict__ Wo,
        const float* __restrict__ nW1, const float* __restrict__ nW2,
        const float* __restrict__ eW1, const float* __restrict__ eW2,
        short* __restrict__ WqkvT, short* __restrict__ WoT,
        short* __restrict__ nW1T, short* __restrict__ nW2T,
        short* __restrict__ eW1T, short* __restrict__ eW2T)
{
    const float* W; short* WT; int Kk, Nn; float sc = 1.f;
    switch (blockIdx.z) {
        case 0: W=Wq;  WT=WqkvT;          Kk=256;  Nn=256;  sc=0.17677669529663687f; break;
        case 1: W=Wk;  WT=WqkvT+256*256;  Kk=256;  Nn=256;  break;
        case 2: W=Wv;  WT=WqkvT+512*256;  Kk=256;  Nn=256;  break;
        case 3: W=Wo;  WT=WoT;            Kk=256;  Nn=256;  break;
        case 4: W=nW1; WT=nW1T;           Kk=256;  Nn=1024; break;
        case 5: W=nW2; WT=nW2T;           Kk=1024; Nn=256;  break;
        case 6: W=eW1; WT=eW1T;           Kk=256;  Nn=1024; break;
        default:W=eW2; WT=eW2T;           Kk=1024; Nn=256;  break;
    }
    const int bx = blockIdx.x, by = blockIdx.y;
    if (bx >= Nn/32 || by >= Kk/32) return;
    __shared__ float tile[32][33];
    int tx = threadIdx.x & 31, ty = threadIdx.x >> 5;   // 32x8
    #pragma unroll
    for (int j = 0; j < 4; ++j) {
        int k = by*32 + ty + j*8;
        tile[ty + j*8][tx] = W[(size_t)k*Nn + bx*32 + tx];
    }
    __syncthreads();
    #pragma unroll
    for (int j = 0; j < 4; ++j) {
        int n = bx*32 + ty + j*8;
        WT[(size_t)n*Kk + by*32 + tx] = bf16s(tile[tx][ty + j*8] * sc);
    }
}

__global__ __launch_bounds__(256) void build_bqkv(const float* __restrict__ bq,
        const float* __restrict__ bk, const float* __restrict__ bv,
        float* __restrict__ bqkv)
{
    int t = blockIdx.x*256 + threadIdx.x;
    if (t >= 768) return;
    float v = (t < 256) ? bq[t]*0.17677669529663687f
            : (t < 512) ? bk[t-256] : bv[t-512];
    bqkv[t] = v;
}

// ---------------- x (N,B,D) f32 -> xtb (B*N, D) bf16 ------------------------
__global__ __launch_bounds__(256) void conv_x(const float* __restrict__ x,
        short* __restrict__ xtb)
{
    int row = blockIdx.x;         // b*N+n
    int d = threadIdx.x;
    int b = row >> 9, n = row & 511;
    xtb[(size_t)row*D_ + d] = bf16s(x[((size_t)n*B_ + b)*D_ + d]);
}

// ---------------- means[b,i,k] = mean_d e ----------------------------------
__global__ __launch_bounds__(256) void edge_means(const float* __restrict__ e,
        float* __restrict__ means)
{
    long row = (long)blockIdx.x*4 + (threadIdx.x >> 6);
    int lane = threadIdx.x & 63;
    float4 v = ((const float4*)(e + row*D_))[lane];
    float s = v.x + v.y + v.z + v.w;
    for (int o = 1; o < 64; o <<= 1) s += __shfl_xor(s, o);
    if (lane == 0) means[row] = s * (1.f/D_);
}

// zero 16 rows + serial per-row scatter (numpy last-wins) in one kernel
__global__ __launch_bounds__(256) void bias_build(const int* __restrict__ ei,
        const float* __restrict__ means, float* __restrict__ biasb)
{
    const int r0 = blockIdx.x * 16;       // 16 (b,i) rows per block
    float4* bp4 = (float4*)(biasb + (size_t)r0*N_);
    #pragma unroll
    for (int i = threadIdx.x; i < 16*N_/4; i += 256)
        bp4[i] = make_float4(0.f, 0.f, 0.f, 0.f);
    __syncthreads();
    if (threadIdx.x < 16) {
        const int idx = r0 + threadIdx.x;
        const int* ep = ei + (size_t)idx*K_;
        const float* mp = means + (size_t)idx*K_;
        float* bp = biasb + (size_t)idx*N_;
        for (int k = 0; k < K_; ++k) bp[ep[k]] = mp[k];
    }
}

// ---------------- generic bf16 MFMA GEMM (128x128): QKV / Wo ----------------
// OUTMODE: 0 = f32 Cf, 2 = qkv split (cols<512 -> Cb[.,512], cols>=512 -> vtb transposed)
template<int OUTMODE>
__global__ __launch_bounds__(256) void gemm_bf16(
        const short* __restrict__ A, const short* __restrict__ BT,
        const float* __restrict__ bias, float* __restrict__ Cf,
        short* __restrict__ Cb, short* __restrict__ vtb, int Nn, int Kk)
{
    __shared__ __align__(16) short As[128*32];
    __shared__ __align__(16) short Bs[128*32];
    const int t = threadIdx.x;
    const int lane = t & 63;
    const int wave = t >> 6;
    const int wr = (wave >> 1) * 64;
    const int wc = (wave & 1) * 64;
    const int bm = blockIdx.x, bn = blockIdx.y;
    f32x4 acc[4][4] = {};
    const int srow = lane >> 2;       // staging row within 16-row group
    const int sk   = (lane & 3) * 8;  // staging k offset (8 bf16 = 16B)
    const int fr = lane & 15;
    const int fk = (lane >> 4) * 8;
    for (int k0 = 0; k0 < Kk; k0 += 32) {
        __syncthreads();
        #pragma unroll
        for (int i = 0; i < 2; ++i) {
            const int rb = wave*16 + i*64;
            gload16(A  + (size_t)(bm*128 + rb + srow)*Kk + k0 + sk, &As[rb*32]);
            gload16(BT + (size_t)(bn*128 + rb + srow)*Kk + k0 + sk, &Bs[rb*32]);
        }
        __syncthreads();
        bf16x8 af[4], bfr[4];
        #pragma unroll
        for (int i2 = 0; i2 < 4; ++i2)
            af[i2] = *(const bf16x8*)&As[(wr + i2*16 + fr)*32 + fk];
        #pragma unroll
        for (int n2 = 0; n2 < 4; ++n2)
            bfr[n2] = *(const bf16x8*)&Bs[(wc + n2*16 + fr)*32 + fk];
        #pragma unroll
        for (int i2 = 0; i2 < 4; ++i2)
            #pragma unroll
            for (int n2 = 0; n2 < 4; ++n2)
                acc[i2][n2] = __builtin_amdgcn_mfma_f32_16x16x32_bf16(
                        af[i2], bfr[n2], acc[i2][n2], 0, 0, 0);
    }
    const int fq4 = (lane >> 4) * 4;
    #pragma unroll
    for (int i2 = 0; i2 < 4; ++i2) {
        #pragma unroll
        for (int n2 = 0; n2 < 4; ++n2) {
            const int col = bn*128 + wc + n2*16 + fr;
            const float bv = bias[col];
            if constexpr (OUTMODE == 2) {
                const int rowb = bm*128 + wr + i2*16 + fq4;
                if (col < 512) {
                    #pragma unroll
                    for (int r2 = 0; r2 < 4; ++r2)
                        Cb[(size_t)(rowb + r2)*512 + col] = bf16s(acc[i2][n2][r2] + bv);
                } else {
                    const int b = rowb >> 9, n = rowb & 511;
                    const int dv = col - 512, h = dv >> 5, dh = dv & 31;
                    short4 s4;
                    s4.x = bf16s(acc[i2][n2][0] + bv);
                    s4.y = bf16s(acc[i2][n2][1] + bv);
                    s4.z = bf16s(acc[i2][n2][2] + bv);
                    s4.w = bf16s(acc[i2][n2][3] + bv);
                    *(short4*)&vtb[((size_t)((b*H_ + h)*HD_ + dh))*512 + n] = s4;
                }
            } else {
                #pragma unroll
                for (int r2 = 0; r2 < 4; ++r2) {
                    const int row = bm*128 + wr + i2*16 + fq4 + r2;
                    Cf[(size_t)row*Nn + col] = acc[i2][n2][r2] + bv;
                }
            }
        }
    }
}

// ---------------- 128x256 8-wave GEMM + GELU -> bf16 (W1 GEMMs) -------------
__global__ __launch_bounds__(512, 4) void gemm_gelu(
        const short* __restrict__ A, const short* __restrict__ BT,
        const float* __restrict__ bias, short* __restrict__ Cb, int Nn, int Kk)
{
    __shared__ __align__(16) short As[128*32];
    __shared__ __align__(16) short Bs[256*32];
    const int t = threadIdx.x;
    const int lane = t & 63;
    const int wave = t >> 6;
    const int wrg = (wave >> 2) * 64;     // row group 0/64
    const int wc  = (wave & 3) * 64;      // col group 0..192
    const int bm = blockIdx.x, bn = blockIdx.y;
    f32x4 acc[4][4] = {};
    const int srow = lane >> 2;
    const int sk   = (lane & 3) * 8;
    const int fr = lane & 15;
    const int fk = (lane >> 4) * 8;
    for (int k0 = 0; k0 < Kk; k0 += 32) {
        __syncthreads();
        {
            const int rb = wave*16;   // A: 128 rows, 1 gload/wave
            gload16(A + (size_t)(bm*128 + rb + srow)*Kk + k0 + sk, &As[rb*32]);
        }
        #pragma unroll
        for (int i = 0; i < 2; ++i) {  // B: 256 rows, 2 gloads/wave
            const int rb = wave*16 + i*128;
            gload16(BT + (size_t)(bn*256 + rb + srow)*Kk + k0 + sk, &Bs[rb*32]);
        }
        __syncthreads();
        bf16x8 af[4], bfr[4];
        #pragma unroll
        for (int i2 = 0; i2 < 4; ++i2)
            af[i2] = *(const bf16x8*)&As[(wrg + i2*16 + fr)*32 + fk];
        #pragma unroll
        for (int n2 = 0; n2 < 4; ++n2)
            bfr[n2] = *(const bf16x8*)&Bs[(wc + n2*16 + fr)*32 + fk];
        #pragma unroll
        for (int i2 = 0; i2 < 4; ++i2)
            #pragma unroll
            for (int n2 = 0; n2 < 4; ++n2)
                acc[i2][n2] = __builtin_amdgcn_mfma_f32_16x16x32_bf16(
                        af[i2], bfr[n2], acc[i2][n2], 0, 0, 0);
    }
    const int fq4 = (lane >> 4) * 4;
    #pragma unroll
    for (int i2 = 0; i2 < 4; ++i2) {
        #pragma unroll
        for (int n2 = 0; n2 < 4; ++n2) {
            const int col = bn*256 + wc + n2*16 + fr;
            const float bv = bias[col];
            #pragma unroll
            for (int r2 = 0; r2 < 4; ++r2) {
                const int row = bm*128 + wrg + i2*16 + fq4 + r2;
                float v = acc[i2][n2][r2] + bv;
                v = 0.5f*v*(1.f + erff(v*0.70710678118654752f));
                Cb[(size_t)row*Nn + col] = bf16s(v);
            }
        }
    }
}

// ------- 128x256 8-wave GEMM + bias + residual + LayerNorm (W2 GEMMs) -------
// RESBF: residual from bf16 buffer (edge) else f32; TRANSOUT: (N,B,D) store
template<bool TRANSOUT, bool RESBF>
__global__ __launch_bounds__(512, 4) void gemm_ln2(
        const short* __restrict__ A, const short* __restrict__ BT,
        const float* __restrict__ bias, const float* __restrict__ resf,
        const short* __restrict__ resb,
        const float* __restrict__ g, const float* __restrict__ bt,
        float* __restrict__ out, int Kk)
{
    __shared__ __align__(16) short As[128*32];
    __shared__ __align__(16) short Bs[256*32];
    __shared__ float rs[128][4][2];
    __shared__ float mr[128][2];
    const int t = threadIdx.x;
    const int lane = t & 63;
    const int wave = t >> 6;
    const int wrg = (wave >> 2) * 64;
    const int wc  = (wave & 3) * 64;
    const int bm = blockIdx.x;
    f32x4 acc[4][4] = {};
    const int srow = lane >> 2;
    const int sk   = (lane & 3) * 8;
    const int fr = lane & 15;
    const int fk = (lane >> 4) * 8;
    for (int k0 = 0; k0 < Kk; k0 += 32) {
        __syncthreads();
        {
            const int rb = wave*16;
            gload16(A + (size_t)(bm*128 + rb + srow)*Kk + k0 + sk, &As[rb*32]);
        }
        #pragma unroll
        for (int i = 0; i < 2; ++i) {
            const int rb = wave*16 + i*128;
            gload16(BT + (size_t)(rb + srow)*Kk + k0 + sk, &Bs[rb*32]);
        }
        __syncthreads();
        bf16x8 af[4], bfr[4];
        #pragma unroll
        for (int i2 = 0; i2 < 4; ++i2)
            af[i2] = *(const bf16x8*)&As[(wrg + i2*16 + fr)*32 + fk];
        #pragma unroll
        for (int n2 = 0; n2 < 4; ++n2)
            bfr[n2] = *(const bf16x8*)&Bs[(wc + n2*16 + fr)*32 + fk];
        #pragma unroll
        for (int i2 = 0; i2 < 4; ++i2)
            #pragma unroll
            for (int n2 = 0; n2 < 4; ++n2)
                acc[i2][n2] = __builtin_amdgcn_mfma_f32_16x16x32_bf16(
                        af[i2], bfr[n2], acc[i2][n2], 0, 0, 0);
    }
    const int fq4 = (lane >> 4) * 4;
    float ps[4][4] = {}, pq[4][4] = {};
    #pragma unroll
    for (int i2 = 0; i2 < 4; ++i2) {
        #pragma unroll
        for (int n2 = 0; n2 < 4; ++n2) {
            const int c = wc + n2*16 + fr;
            const float bv = bias[c];
            #pragma unroll
            for (int r2 = 0; r2 < 4; ++r2) {
                const int row = wrg + i2*16 + fq4 + r2;
                const size_t grow = (size_t)bm*128 + row;
                float rv;
                if constexpr (RESBF) rv = b2f(resb[grow*256 + c]);
                else                 rv = resf[grow*256 + c];
                float v = acc[i2][n2][r2] + bv + rv;
                acc[i2][n2][r2] = v;
                ps[i2][r2] += v;
                pq[i2][r2] += v*v;
            }
        }
    }
    #pragma unroll
    for (int i2 = 0; i2 < 4; ++i2)
        #pragma unroll
        for (int r2 = 0; r2 < 4; ++r2)
            #pragma unroll
            for (int o = 1; o < 16; o <<= 1) {
                ps[i2][r2] += __shfl_xor(ps[i2][r2], o);
                pq[i2][r2] += __shfl_xor(pq[i2][r2], o);
            }
    if ((lane & 15) == 0) {
        #pragma unroll
        for (int i2 = 0; i2 < 4; ++i2)
            #pragma unroll
            for (int r2 = 0; r2 < 4; ++r2) {
                const int row = wrg + i2*16 + fq4 + r2;
                rs[row][wave & 3][0] = ps[i2][r2];
                rs[row][wave & 3][1] = pq[i2][r2];
            }
    }
    __syncthreads();
    if (t < 128) {
        float S = 0.f, Q = 0.f;
        #pragma unroll
        for (int w = 0; w < 4; ++w) { S += rs[t][w][0]; Q += rs[t][w][1]; }
        const float mean = S * (1.f/D_);
        mr[t][0] = mean;
        mr[t][1] = rsqrtf(Q * (1.f/D_) - mean*mean + 1e-5f);
    }
    __syncthreads();
    #pragma unroll
    for (int i2 = 0; i2 < 4; ++i2) {
        #pragma unroll
        for (int n2 = 0; n2 < 4; ++n2) {
            const int c = wc + n2*16 + fr;
            const float gv = g[c], bv2 = bt[c];
            #pragma unroll
            for (int r2 = 0; r2 < 4; ++r2) {
                const int row = wrg + i2*16 + fq4 + r2;
                const size_t grow = (size_t)bm*128 + row;
                const float o = (acc[i2][n2][r2] - mr[row][0])*mr[row][1]*gv + bv2;
                if constexpr (TRANSOUT) {
                    const int bb = (int)(grow >> 9), nn = (int)(grow & 511);
                    out[((size_t)nn*B_ + bb)*D_ + c] = o;
                } else {
                    out[grow*256 + c] = o;
                }
            }
        }
    }
}

// ---------------- fused flash attention: QK^T+bias -> exp -> PV -------------
__global__ __launch_bounds__(256) void attn_fused(const short* __restrict__ qkb,
        const short* __restrict__ vtb, const float* __restrict__ biasb,
        float* __restrict__ rowsum, short* __restrict__ actx)
{
    __shared__ __align__(16) short Qs[128*32];
    __shared__ __align__(16) short Ks[128*32];
    __shared__ __align__(16) short Vs[32*128];     // [dh][j], source-pre-swizzled
    __shared__ __align__(16) short Ps[128*128];    // XOR-swizzled bf16 P tile
    const int it = blockIdx.x, bh = blockIdx.y;
    const int b = bh >> 3, h = bh & 7;
    const int t = threadIdx.x;
    const int lane = t & 63;
    const int wave = t >> 6;
    const int wr0 = wave * 32;
    const int srow = lane >> 2;        // staging: 16 rows x 64B
    const int sk   = (lane & 3) * 8;
    const int srow8 = lane >> 4;       // staging: 4 rows x 256B
    const int ck16  = lane & 15;       // 16B chunk index within 128-col row
    const int fr = lane & 15;
    const int fk = (lane >> 4) * 8;
    const int fq4 = (lane >> 4) * 4;
    const int I0 = it * 128;
    #pragma unroll
    for (int i = 0; i < 2; ++i) {
        const int rb = wave*16 + i*64;
        gload16(qkb + (size_t)(b*N_ + I0 + rb + srow)*512 + h*HD_ + sk, &Qs[rb*32]);
    }
    float rsum[2][4] = {};
    f32x4 apv[2][2] = {};
    const float LOG2E = 1.4426950408889634f;
    for (int jt = 0; jt < 4; ++jt) {
        const int J0 = jt * 128;
        __syncthreads();
        #pragma unroll
        for (int i = 0; i < 2; ++i) {
            const int rb = wave*16 + i*64;
            gload16(qkb + (size_t)(b*N_ + J0 + rb + srow)*512 + 256 + h*HD_ + sk, &Ks[rb*32]);
        }
        #pragma unroll
        for (int i = 0; i < 2; ++i) {
            const int db = wave*8 + i*4;
            const int dh = db + srow8;
            gload16(vtb + ((size_t)bh*HD_ + dh)*512 + J0 + ((ck16 ^ (dh & 7)) * 8),
                    &Vs[db*128]);
        }
        __syncthreads();
        bf16x8 aq[2], kf8[8];
        #pragma unroll
        for (int i2 = 0; i2 < 2; ++i2)
            aq[i2] = *(const bf16x8*)&Qs[(wr0 + i2*16 + fr)*32 + fk];
        #pragma unroll
        for (int n2 = 0; n2 < 8; ++n2)
            kf8[n2] = *(const bf16x8*)&Ks[(n2*16 + fr)*32 + fk];
        #pragma unroll
        for (int i2 = 0; i2 < 2; ++i2) {
            #pragma unroll
            for (int n2 = 0; n2 < 8; ++n2) {
                f32x4 z = {0.f, 0.f, 0.f, 0.f};
                f32x4 s = __builtin_amdgcn_mfma_f32_16x16x32_bf16(aq[i2], kf8[n2], z, 0, 0, 0);
                const int jg = J0 + n2*16 + fr;
                #pragma unroll
                for (int r2 = 0; r2 < 4; ++r2) {
                    const int rloc = wr0 + i2*16 + fq4 + r2;
                    const float l = s[r2] + biasb[((size_t)b*N_ + I0 + rloc)*N_ + jg];
                    const float p = exp2f(fminf(l, 80.f) * LOG2E);
                    rsum[i2][r2] += p;
                    int idx = rloc*128 + n2*16 + fr;
                    idx ^= (rloc & 7) << 3;
                    Ps[idx] = bf16s(p);
                }
            }
        }
        __syncthreads();
        #pragma unroll
        for (int ks = 0; ks < 4; ++ks) {
            bf16x8 ap[2], bv[2];
            #pragma unroll
            for (int i2 = 0; i2 < 2; ++i2) {
                const int r = wr0 + i2*16 + fr;
                int idx = r*128 + ks*32 + fk;
                idx ^= (r & 7) << 3;
                ap[i2] = *(const bf16x8*)&Ps[idx];
            }
            #pragma unroll
            for (int n2 = 0; n2 < 2; ++n2) {
                const int dh = n2*16 + fr;
                const int q = lane >> 4;
                const int slot = (ks*4 + q) ^ (dh & 7);
                bv[n2] = *(const bf16x8*)&Vs[dh*128 + slot*8];
            }
            #pragma unroll
            for (int i2 = 0; i2 < 2; ++i2)
                #pragma unroll
                for (int n2 = 0; n2 < 2; ++n2)
                    apv[i2][n2] = __builtin_amdgcn_mfma_f32_16x16x32_bf16(
                            ap[i2], bv[n2], apv[i2][n2], 0, 0, 0);
        }
    }
    #pragma unroll
    for (int i2 = 0; i2 < 2; ++i2)
        #pragma unroll
        for (int r2 = 0; r2 < 4; ++r2)
            #pragma unroll
            for (int o = 1; o < 16; o <<= 1)
                rsum[i2][r2] += __shfl_xor(rsum[i2][r2], o);
    #pragma unroll
    for (int i2 = 0; i2 < 2; ++i2) {
        #pragma unroll
        for (int r2 = 0; r2 < 4; ++r2) {
            const int row = wr0 + i2*16 + fq4 + r2;
            if (fr == 0)
                rowsum[(size_t)bh*N_ + I0 + row] = rsum[i2][r2];
            const float inv = 1.f / rsum[i2][r2];
            #pragma unroll
            for (int n2 = 0; n2 < 2; ++n2)
                actx[((size_t)b*N_ + I0 + row)*D_ + h*HD_ + n2*16 + fr]
                    = bf16s(apv[i2][n2][r2] * inv);
        }
    }
}

// ---------------- LN helpers (wave per row of 256) ---------------------------
__device__ inline void ln_core(float v[4], int lane, const float* __restrict__ g,
        const float* __restrict__ bt, float out[4])
{
    float s  = v[0] + v[1] + v[2] + v[3];
    float sq = v[0]*v[0] + v[1]*v[1] + v[2]*v[2] + v[3]*v[3];
    for (int o = 1; o < 64; o <<= 1) { s += __shfl_xor(s, o); sq += __shfl_xor(sq, o); }
    float mean = s * (1.f/D_);
    float rstd = rsqrtf(sq * (1.f/D_) - mean*mean + 1e-5f);
    const float4 gv = *(const float4*)(g  + lane*4);
    const float4 bv = *(const float4*)(bt + lane*4);
    out[0] = (v[0]-mean)*rstd*gv.x + bv.x;
    out[1] = (v[1]-mean)*rstd*gv.y + bv.y;
    out[2] = (v[2]-mean)*rstd*gv.z + bv.z;
    out[3] = (v[3]-mean)*rstd*gv.w + bv.w;
}

// xn = LN(x^T + aout); writes f32 + bf16
__global__ __launch_bounds__(256) void ln_xn(const float* __restrict__ x,
        const float* __restrict__ aout, const float* __restrict__ g,
        const float* __restrict__ bt, float* __restrict__ xn, short* __restrict__ xnb)
{
    int row = blockIdx.x*4 + (threadIdx.x >> 6);
    int lane = threadIdx.x & 63;
    int b = row >> 9, n = row & 511;
    const float4 xv = *(const float4*)(x + ((size_t)n*B_ + b)*D_ + lane*4);
    const float4 av = *(const float4*)(aout + (size_t)row*D_ + lane*4);
    float v[4] = {xv.x+av.x, xv.y+av.y, xv.z+av.z, xv.w+av.w};
    float o[4];
    ln_core(v, lane, g, bt, o);
    *(float4*)(xn + (size_t)row*D_ + lane*4) = make_float4(o[0], o[1], o[2], o[3]);
    short4 s4; s4.x = bf16s(o[0]); s4.y = bf16s(o[1]); s4.z = bf16s(o[2]); s4.w = bf16s(o[3]);
    *(short4*)(xnb + (size_t)row*D_ + lane*4) = s4;
}

// e2 = LN(e + w*gathered), w recomputed from q,k,bias,rowsum; writes bf16 only
__global__ __launch_bounds__(256) void edge_update(const float* __restrict__ e,
        const float* __restrict__ x, const int* __restrict__ ei,
        const short* __restrict__ qkb, const float* __restrict__ biasb,
        const float* __restrict__ rowsum, const float* __restrict__ g,
        const float* __restrict__ bt, short* __restrict__ e2b)
{
    long row = (long)blockIdx.x*4 + (threadIdx.x >> 6);   // b*N*K + i*K + k
    int lane = threadIdx.x & 63;
    long bi = row >> 4;          // / K_
    long b = bi / N_; int i = (int)(bi % N_);
    int ej = ei[row];
    const short4 q4 = *(const short4*)(qkb + ((size_t)b*N_ + ej)*512 + lane*4);
    const short4 k4 = *(const short4*)(qkb + ((size_t)b*N_ + i)*512 + 256 + lane*4);
    float dot = b2f(q4.x)*b2f(k4.x) + b2f(q4.y)*b2f(k4.y)
              + b2f(q4.z)*b2f(k4.z) + b2f(q4.w)*b2f(k4.w);
    dot += __shfl_xor(dot, 1); dot += __shfl_xor(dot, 2); dot += __shfl_xor(dot, 4);
    const int h = lane >> 3;
    const float l = dot + biasb[((size_t)b*N_ + ej)*N_ + i];
    float p = exp2f(fminf(l, 80.f) * 1.4426950408889634f)
            / rowsum[((size_t)b*H_ + h)*N_ + ej];
    p += __shfl_xor(p, 8); p += __shfl_xor(p, 16); p += __shfl_xor(p, 32);
    const float w = p * (1.f/H_);
    const float4 ev = *(const float4*)(e + row*D_ + lane*4);
    const float4 xv = *(const float4*)(x + ((size_t)ej*B_ + b)*D_ + lane*4);
    float v[4] = {ev.x + w*xv.x, ev.y + w*xv.y, ev.z + w*xv.z, ev.w + w*xv.w};
    float o[4];
    ln_core(v, lane, g, bt, o);
    short4 s4; s4.x = bf16s(o[0]); s4.y = bf16s(o[1]); s4.z = bf16s(o[2]); s4.w = bf16s(o[3]);
    *(short4*)(e2b + row*D_ + lane*4) = s4;
}

// ============================================================================
extern "C" void kernel_launch(void* const* d_in, const int* in_sizes, int n_in,
                              void* d_out, int out_size, void* d_ws, size_t ws_size,
                              hipStream_t stream)
{
    (void)in_sizes; (void)n_in; (void)out_size; (void)ws_size;
    const float* x    = (const float*)d_in[0];
    const float* e    = (const float*)d_in[1];
    const int*   ei   = (const int*)d_in[2];
    const float* Wq   = (const float*)d_in[3];
    const float* bq   = (const float*)d_in[4];
    const float* Wk   = (const float*)d_in[5];
    const float* bk   = (const float*)d_in[6];
    const float* Wv   = (const float*)d_in[7];
    const float* bv   = (const float*)d_in[8];
    const float* Wo   = (const float*)d_in[9];
    const float* bo   = (const float*)d_in[10];
    const float* nW1  = (const float*)d_in[11];
    const float* nb1  = (const float*)d_in[12];
    const float* nW2  = (const float*)d_in[13];
    const float* nb2  = (const float*)d_in[14];
    const float* eW1  = (const float*)d_in[15];
    const float* eb1  = (const float*)d_in[16];
    const float* eW2  = (const float*)d_in[17];
    const float* eb2  = (const float*)d_in[18];
    const float* na_g = (const float*)d_in[19];
    const float* na_b = (const float*)d_in[20];
    const float* ea_g = (const float*)d_in[21];
    const float* ea_b = (const float*)d_in[22];
    const float* nf_g = (const float*)d_in[23];
    const float* nf_b = (const float*)d_in[24];
    const float* ef_g = (const float*)d_in[25];
    const float* ef_b = (const float*)d_in[26];

    float* out1 = (float*)d_out;                       // (N,B,D)
    float* e2f  = out1 + (size_t)N_*B_*D_;             // (B,N,K,D) final

    // ---- workspace: fixed region + overlay (pre-MLP buffers alias ehid) ----
    char* wp = (char*)d_ws;
    auto alloc = [&](size_t bytes) -> char* {
        char* p = wp; wp += (bytes + 255) & ~(size_t)255; return p;
    };
    // fixed (live across phases)
    short* WqkvT  = (short*)alloc((size_t)768*D_*2);
    float* bqkv   = (float*)alloc(768*4);
    short* WoT    = (short*)alloc((size_t)D_*D_*2);
    short* nW1T   = (short*)alloc((size_t)F_*D_*2);
    short* nW2T   = (short*)alloc((size_t)D_*F_*2);
    short* eW1T   = (short*)alloc((size_t)F_*D_*2);
    short* eW2T   = (short*)alloc((size_t)D_*F_*2);
    float* rowsum = (float*)alloc((size_t)B_*H_*N_*4);
    short* e2b    = (short*)alloc((size_t)R_*D_*2);
    // overlay: phase-A buffers (dead before edge MLP) alias ehid
    char* ov = wp;
    auto allocA = [&](size_t bytes) -> char* {
        char* p = ov; ov += (bytes + 255) & ~(size_t)255; return p;
    };
    short* xtb    = (short*)allocA((size_t)M_*D_*2);
    float* means  = (float*)allocA((size_t)R_*4);
    float* biasb  = (float*)allocA((size_t)B_*N_*N_*4);
    short* qkb    = (short*)allocA((size_t)M_*512*2);
    short* vtb    = (short*)allocA((size_t)B_*H_*HD_*N_*2);
    short* actx   = (short*)allocA((size_t)M_*D_*2);
    float* aout   = (float*)allocA((size_t)M_*D_*4);
    float* xn     = (float*)allocA((size_t)M_*D_*4);
    short* xnb    = (short*)allocA((size_t)M_*D_*2);
    short* nhid   = (short*)allocA((size_t)M_*F_*2);
    short* ehid   = (short*)wp;   // (R_, F_) bf16 = 134 MB, aliases all of phase-A

    // ---- weight prep (1 launch) + bias vector ----
    transposeAll<<<dim3(32, 32, 8), 256, 0, stream>>>(Wq, Wk, Wv, Wo,
            nW1, nW2, eW1, eW2, WqkvT, WoT, nW1T, nW2T, eW1T, eW2T);
    build_bqkv<<<3, 256, 0, stream>>>(bq, bk, bv, bqkv);
    conv_x<<<M_, 256, 0, stream>>>(x, xtb);

    // ---- attn bias ----
    edge_means<<<R_/4, 256, 0, stream>>>(e, means);
    bias_build<<<M_/16, 256, 0, stream>>>(ei, means, biasb);

    // ---- QKV (fused, q-scale folded into Wq/bq) ----
    gemm_bf16<2><<<dim3(M_/128, 768/128), 256, 0, stream>>>(
            xtb, WqkvT, bqkv, nullptr, qkb, vtb, 768, D_);

    // ---- attention (fused flash-style) ----
    attn_fused<<<dim3(N_/128, B_*H_), 256, 0, stream>>>(qkb, vtb, biasb, rowsum, actx);
    gemm_bf16<0><<<dim3(M_/128, D_/128), 256, 0, stream>>>(
            actx, WoT, bo, aout, nullptr, nullptr, D_, D_);

    // ---- node path ----
    ln_xn<<<M_/4, 256, 0, stream>>>(x, aout, na_g, na_b, xn, xnb);
    gemm_gelu<<<dim3(M_/128, F_/256), 512, 0, stream>>>(
            xnb, nW1T, nb1, nhid, F_, D_);
    gemm_ln2<true,false><<<M_/128, 512, 0, stream>>>(
            nhid, nW2T, nb2, xn, nullptr, nf_g, nf_b, out1, F_);

    // ---- edge path (single full-size pass; ehid overlays dead buffers) ----
    edge_update<<<R_/4, 256, 0, stream>>>(e, x, ei, qkb, biasb, rowsum,
            ea_g, ea_b, e2b);
    gemm_gelu<<<dim3(R_/128, F_/256), 512, 0, stream>>>(
            e2b, eW1T, eb1, ehid, F_, D_);
    gemm_ln2<false,true><<<R_/128, 512, 0, stream>>>(
            ehid, eW2T, eb2, nullptr, e2b, ef_g, ef_b, e2f, F_);
}